// Round 2
// baseline (2418.974 us; speedup 1.0000x reference)
//
#include <hip/hip_runtime.h>

#define N_GENE 50000
#define N_PATH 20000
#define N_VACC 10000
#define N_TOT  80000
#define HID    128
#define E_PER  250000
#define OG 0
#define OP 50000
#define OV 70000

typedef __bf16 bf16x8 __attribute__((ext_vector_type(8)));
typedef float  f32x4  __attribute__((ext_vector_type(4)));

// ---------------- CSR build ----------------

__global__ void count_kernel(const int* __restrict__ dst, int n, int* __restrict__ cnt, int doff)
{
    int e = blockIdx.x * 256 + threadIdx.x;
    if (e < n) atomicAdd(&cnt[dst[e] + doff], 1);
}

__global__ void scan_kernel(const int* __restrict__ cnt, int* __restrict__ off, int n)
{
    __shared__ int sh[1024];
    int t = threadIdx.x;
    int chunk = (n + 1023) >> 10;
    int lo = t * chunk, hi = min(n, lo + chunk);
    int s = 0;
    for (int i = lo; i < hi; i++) s += cnt[i];
    sh[t] = s;
    __syncthreads();
    for (int d = 1; d < 1024; d <<= 1) {
        int v = (t >= d) ? sh[t - d] : 0;
        __syncthreads();
        sh[t] += v;
        __syncthreads();
    }
    int run = sh[t] - s;  // exclusive prefix
    for (int i = lo; i < hi; i++) { off[i] = run; run += cnt[i]; }
    if (t == 1023) off[n] = run;
}

__global__ void dinv_kernel(const int* __restrict__ off, float* __restrict__ dinv, int n)
{
    int i = blockIdx.x * 256 + threadIdx.x;
    if (i < n) dinv[i] = rsqrtf((float)(off[i + 1] - off[i] + 1));  // +1 self loop
}

__global__ void fill_rel_kernel(const int* __restrict__ ei, int n,
                                const int* __restrict__ off, int* __restrict__ cur,
                                int* __restrict__ rows)
{
    int e = blockIdx.x * 256 + threadIdx.x;
    if (e < n) {
        int s = ei[e], d = ei[n + e];
        int pos = off[d] + atomicAdd(&cur[d], 1);
        rows[pos] = s;
    }
}

__global__ void fill_appnp_kernel(const int* __restrict__ ei, int n, int soff, int doff,
                                  const int* __restrict__ off, int* __restrict__ cur,
                                  int* __restrict__ rows, float* __restrict__ wts,
                                  const float* __restrict__ dinv)
{
    int e = blockIdx.x * 256 + threadIdx.x;
    if (e < n) {
        int s = ei[e] + soff, d = ei[n + e] + doff;
        int pos = off[d] + atomicAdd(&cur[d], 1);
        rows[pos] = s;
        wts[pos] = dinv[s];
    }
}

// ---------------- gather kernels ----------------

__global__ void agg_kernel(const float* __restrict__ hsrc, const int* __restrict__ rows,
                           const int* __restrict__ off, float* __restrict__ out)
{
    int d = blockIdx.x, t = threadIdx.x;  // 128 threads: one per feature
    int s = off[d], e = off[d + 1];
    float acc = 0.f;
    for (int i = s; i < e; i++) acc += hsrc[(size_t)rows[i] * HID + t];
    float inv = (e > s) ? 1.0f / (float)(e - s) : 0.0f;
    out[(size_t)d * HID + t] = acc * inv;
}

__global__ void appnp_kernel(const float* __restrict__ zin, float* __restrict__ zout,
                             const float* __restrict__ h0,
                             const int* __restrict__ rows, const float* __restrict__ wts,
                             const int* __restrict__ off, const float* __restrict__ dinv)
{
    int c = blockIdx.x, t = threadIdx.x;  // 128 threads: one per feature
    int s = off[c], e = off[c + 1];
    float acc = 0.f;
    for (int i = s; i < e; i++) acc += wts[i] * zin[(size_t)rows[i] * HID + t];
    float dc = dinv[c];
    size_t idx = (size_t)c * HID + t;
    zout[idx] = 0.9f * (dc * acc + dc * dc * zin[idx]) + 0.1f * h0[idx];
}

// ---------------- weight f32 -> bf16 conversion ----------------

__global__ void cvtbf_kernel(const float* __restrict__ src, __bf16* __restrict__ dst, int n)
{
    int i = blockIdx.x * 256 + threadIdx.x;
    if (i < n) dst[i] = (__bf16)src[i];
}

// ---------------- MFMA GEMM: OUT[M,128] (op)= A[M,K] @ W[128,K]^T (+bias) ----------------
// A is f32 (converted in-register); W pre-converted bf16. One wave per 16-row strip,
// 8 col-tiles of 16. Verified layouts (m89/m91/m120): A[m=lane&15][k=quad*8+j];
// B: n=lane&15, same k slice (W row-major contiguous); C/D: col=lane&15, row=quad*4+reg.

template<int K, bool ACCUM, bool RELU>
__launch_bounds__(256)
__global__ void gemm_kernel(const float* __restrict__ A, const __bf16* __restrict__ W,
                            const float* __restrict__ bias, float* __restrict__ OUT, int M)
{
    int wave = threadIdx.x >> 6;
    int lane = threadIdx.x & 63;
    int m0 = (blockIdx.x * 4 + wave) * 16;
    if (m0 >= M) return;
    int r = lane & 15;
    int quad = lane >> 4;

    f32x4 acc[8];
#pragma unroll
    for (int i = 0; i < 8; i++) acc[i] = (f32x4){0.f, 0.f, 0.f, 0.f};

    for (int k0 = 0; k0 < K; k0 += 32) {
        const float* ap = A + (size_t)(m0 + r) * K + k0 + quad * 8;
        f32x4 f0 = *(const f32x4*)ap;
        f32x4 f1 = *(const f32x4*)(ap + 4);
        bf16x8 a;
        a[0] = (__bf16)f0[0]; a[1] = (__bf16)f0[1]; a[2] = (__bf16)f0[2]; a[3] = (__bf16)f0[3];
        a[4] = (__bf16)f1[0]; a[5] = (__bf16)f1[1]; a[6] = (__bf16)f1[2]; a[7] = (__bf16)f1[3];
#pragma unroll
        for (int nt = 0; nt < 8; nt++) {
            bf16x8 b = *(const bf16x8*)(W + (size_t)(nt * 16 + r) * K + k0 + quad * 8);
            acc[nt] = __builtin_amdgcn_mfma_f32_16x16x32_bf16(a, b, acc[nt], 0, 0, 0);
        }
    }
#pragma unroll
    for (int nt = 0; nt < 8; nt++) {
        int n = nt * 16 + r;
        float bv = bias ? bias[n] : 0.0f;
#pragma unroll
        for (int i = 0; i < 4; i++) {
            size_t idx = (size_t)(m0 + quad * 4 + i) * HID + n;
            float v = acc[nt][i] + bv;
            if (RELU) v = fmaxf(v, 0.f);
            if (ACCUM) OUT[idx] += v;
            else OUT[idx] = v;
        }
    }
}

// ---------------- elementwise ----------------

__global__ void finalize_kernel(float* __restrict__ H, const float* __restrict__ og,
                                const float* __restrict__ opb)
{
    int i = blockIdx.x * 256 + threadIdx.x;
    if (i >= N_TOT * HID) return;
    int row = i >> 7;
    float v = H[i];
    if (row < OP)      v = v + og[i] * (1.0f / 3.0f);
    else if (row < OV) v = v + opb[i - OP * HID];
    H[i] = fmaxf(v, 0.f);
}

// ---------------- driver ----------------

extern "C" void kernel_launch(void* const* d_in, const int* in_sizes, int n_in,
                              void* d_out, int out_size, void* d_ws, size_t ws_size,
                              hipStream_t stream)
{
    (void)in_sizes; (void)n_in; (void)out_size; (void)ws_size;

    const float* x_gene = (const float*)d_in[0];
    const float* x_path = (const float*)d_in[1];
    const float* x_vacc = (const float*)d_in[2];
    const float* win_g  = (const float*)d_in[3];
    const float* bin_g  = (const float*)d_in[4];
    const float* win_p  = (const float*)d_in[5];
    const float* bin_p  = (const float*)d_in[6];
    const float* win_v  = (const float*)d_in[7];
    const float* bin_v  = (const float*)d_in[8];
    const float* wsl    = (const float*)d_in[9];
    const float* bsl    = (const float*)d_in[10];
    const float* wsr    = (const float*)d_in[11];
    const int* ei_tg  = (const int*)d_in[12];  // vaccine -> gene
    const int* ei_ing = (const int*)d_in[13];  // gene -> pathway
    const int* ei_ct  = (const int*)d_in[14];  // pathway -> gene
    const int* ei_ii  = (const int*)d_in[15];  // gene -> gene

    char* p = (char*)d_ws;
    auto alloc = [&](size_t b) { char* r = p; p += (b + 255) & ~((size_t)255); return r; };

    float* H    = (float*)alloc((size_t)N_TOT * HID * 4);
    float* Z1   = (float*)alloc((size_t)N_TOT * HID * 4);
    float* Z2   = (float*)alloc((size_t)N_TOT * HID * 4);
    float* OUTG = (float*)alloc((size_t)N_GENE * HID * 4);
    float* OUTP = (float*)alloc((size_t)N_PATH * HID * 4);
    float* AGG  = (float*)alloc((size_t)N_GENE * HID * 4);
    int*   a_rows = (int*)alloc((size_t)4 * E_PER * 4);
    float* a_wts  = (float*)alloc((size_t)4 * E_PER * 4);
    int*   a_off  = (int*)alloc((size_t)(N_TOT + 1) * 4);
    float* dinv   = (float*)alloc((size_t)N_TOT * 4);
    int* r_rows[4], *r_off[4];
    for (int r = 0; r < 4; r++) r_rows[r] = (int*)alloc((size_t)E_PER * 4);
    for (int r = 0; r < 4; r++) r_off[r]  = (int*)alloc((size_t)(N_GENE + 1) * 4);
    // bf16 weight shadows
    __bf16* wbf_g = (__bf16*)alloc((size_t)HID * 256 * 2);
    __bf16* wbf_p = (__bf16*)alloc((size_t)HID * 128 * 2);
    __bf16* wbf_v = (__bf16*)alloc((size_t)HID * 64 * 2);
    __bf16* wbf_l = (__bf16*)alloc((size_t)2 * 4 * HID * HID * 2);
    __bf16* wbf_r = (__bf16*)alloc((size_t)2 * 4 * HID * HID * 2);
    // zero-init block (one memset)
    char* zb = p;
    int* a_cnt = (int*)alloc((size_t)N_TOT * 4);
    int* a_cur = (int*)alloc((size_t)N_TOT * 4);
    int* r_cnt = (int*)alloc((size_t)4 * N_GENE * 4);
    int* r_cur = (int*)alloc((size_t)4 * N_GENE * 4);
    hipMemsetAsync(zb, 0, (size_t)(p - zb), stream);

    const int GE = (E_PER + 255) / 256;
    const int GB_G = (N_GENE / 16 + 3) / 4;          // 782
    const int GB_P = (N_PATH / 16 + 3) / 4;          // 313
    const int GB_V = (N_VACC / 16 + 3) / 4;          // 157

    // --- weight conversion ---
    cvtbf_kernel<<<(HID * 256 + 255) / 256, 256, 0, stream>>>(win_g, wbf_g, HID * 256);
    cvtbf_kernel<<<(HID * 128 + 255) / 256, 256, 0, stream>>>(win_p, wbf_p, HID * 128);
    cvtbf_kernel<<<(HID * 64 + 255) / 256, 256, 0, stream>>>(win_v, wbf_v, HID * 64);
    cvtbf_kernel<<<(2 * 4 * HID * HID + 255) / 256, 256, 0, stream>>>(wsl, wbf_l, 2 * 4 * HID * HID);
    cvtbf_kernel<<<(2 * 4 * HID * HID + 255) / 256, 256, 0, stream>>>(wsr, wbf_r, 2 * 4 * HID * HID);

    // --- CSR builds ---
    count_kernel<<<GE, 256, 0, stream>>>(ei_tg + E_PER, E_PER, a_cnt, OG);
    count_kernel<<<GE, 256, 0, stream>>>(ei_ing + E_PER, E_PER, a_cnt, OP);
    count_kernel<<<GE, 256, 0, stream>>>(ei_ct + E_PER, E_PER, a_cnt, OG);
    count_kernel<<<GE, 256, 0, stream>>>(ei_ii + E_PER, E_PER, a_cnt, OG);
    count_kernel<<<GE, 256, 0, stream>>>(ei_tg + E_PER, E_PER, r_cnt + 0 * N_GENE, 0);
    count_kernel<<<GE, 256, 0, stream>>>(ei_ing + E_PER, E_PER, r_cnt + 1 * N_GENE, 0);
    count_kernel<<<GE, 256, 0, stream>>>(ei_ct + E_PER, E_PER, r_cnt + 2 * N_GENE, 0);
    count_kernel<<<GE, 256, 0, stream>>>(ei_ii + E_PER, E_PER, r_cnt + 3 * N_GENE, 0);

    scan_kernel<<<1, 1024, 0, stream>>>(a_cnt, a_off, N_TOT);
    scan_kernel<<<1, 1024, 0, stream>>>(r_cnt + 0 * N_GENE, r_off[0], N_GENE);
    scan_kernel<<<1, 1024, 0, stream>>>(r_cnt + 1 * N_GENE, r_off[1], N_PATH);
    scan_kernel<<<1, 1024, 0, stream>>>(r_cnt + 2 * N_GENE, r_off[2], N_GENE);
    scan_kernel<<<1, 1024, 0, stream>>>(r_cnt + 3 * N_GENE, r_off[3], N_GENE);

    dinv_kernel<<<(N_TOT + 255) / 256, 256, 0, stream>>>(a_off, dinv, N_TOT);

    fill_appnp_kernel<<<GE, 256, 0, stream>>>(ei_tg, E_PER, OV, OG, a_off, a_cur, a_rows, a_wts, dinv);
    fill_appnp_kernel<<<GE, 256, 0, stream>>>(ei_ing, E_PER, OG, OP, a_off, a_cur, a_rows, a_wts, dinv);
    fill_appnp_kernel<<<GE, 256, 0, stream>>>(ei_ct, E_PER, OP, OG, a_off, a_cur, a_rows, a_wts, dinv);
    fill_appnp_kernel<<<GE, 256, 0, stream>>>(ei_ii, E_PER, OG, OG, a_off, a_cur, a_rows, a_wts, dinv);
    fill_rel_kernel<<<GE, 256, 0, stream>>>(ei_tg, E_PER, r_off[0], r_cur + 0 * N_GENE, r_rows[0]);
    fill_rel_kernel<<<GE, 256, 0, stream>>>(ei_ing, E_PER, r_off[1], r_cur + 1 * N_GENE, r_rows[1]);
    fill_rel_kernel<<<GE, 256, 0, stream>>>(ei_ct, E_PER, r_off[2], r_cur + 2 * N_GENE, r_rows[2]);
    fill_rel_kernel<<<GE, 256, 0, stream>>>(ei_ii, E_PER, r_off[3], r_cur + 3 * N_GENE, r_rows[3]);

    // --- input projections (relu) ---
    gemm_kernel<256, false, true><<<GB_G, 256, 0, stream>>>(x_gene, wbf_g, bin_g, H, N_GENE);
    gemm_kernel<128, false, true><<<GB_P, 256, 0, stream>>>(x_path, wbf_p, bin_p, H + (size_t)OP * HID, N_PATH);
    gemm_kernel< 64, false, true><<<GB_V, 256, 0, stream>>>(x_vacc, wbf_v, bin_v, H + (size_t)OV * HID, N_VACC);

    // --- 2 hetero-SAGE layers ---
    for (int l = 0; l < 2; l++) {
        const __bf16* WL = wbf_l + (size_t)l * 4 * HID * HID;
        const float*  BL = bsl + (size_t)l * 4 * HID;
        const __bf16* WR = wbf_r + (size_t)l * 4 * HID * HID;

        // rel 0: targets (src=vaccine, dst=gene)  -> OUTG (write)
        agg_kernel<<<N_GENE, 128, 0, stream>>>(H + (size_t)OV * HID, r_rows[0], r_off[0], AGG);
        gemm_kernel<128, false, false><<<GB_G, 256, 0, stream>>>(AGG, WL + 0 * HID * HID, BL + 0 * HID, OUTG, N_GENE);
        gemm_kernel<128, true, false><<<GB_G, 256, 0, stream>>>(H, WR + 0 * HID * HID, nullptr, OUTG, N_GENE);
        // rel 2: contains (src=pathway, dst=gene) -> OUTG (+=)
        agg_kernel<<<N_GENE, 128, 0, stream>>>(H + (size_t)OP * HID, r_rows[2], r_off[2], AGG);
        gemm_kernel<128, true, false><<<GB_G, 256, 0, stream>>>(AGG, WL + 2 * HID * HID, BL + 2 * HID, OUTG, N_GENE);
        gemm_kernel<128, true, false><<<GB_G, 256, 0, stream>>>(H, WR + 2 * HID * HID, nullptr, OUTG, N_GENE);
        // rel 3: interacts (src=gene, dst=gene)   -> OUTG (+=)
        agg_kernel<<<N_GENE, 128, 0, stream>>>(H, r_rows[3], r_off[3], AGG);
        gemm_kernel<128, true, false><<<GB_G, 256, 0, stream>>>(AGG, WL + 3 * HID * HID, BL + 3 * HID, OUTG, N_GENE);
        gemm_kernel<128, true, false><<<GB_G, 256, 0, stream>>>(H, WR + 3 * HID * HID, nullptr, OUTG, N_GENE);
        // rel 1: in (src=gene, dst=pathway)       -> OUTP
        agg_kernel<<<N_PATH, 128, 0, stream>>>(H, r_rows[1], r_off[1], AGG);
        gemm_kernel<128, false, false><<<GB_P, 256, 0, stream>>>(AGG, WL + 1 * HID * HID, BL + 1 * HID, OUTP, N_PATH);
        gemm_kernel<128, true, false><<<GB_P, 256, 0, stream>>>(H + (size_t)OP * HID, WR + 1 * HID * HID, nullptr, OUTP, N_PATH);

        finalize_kernel<<<(N_TOT * HID + 255) / 256, 256, 0, stream>>>(H, OUTG, OUTP);
    }

    // --- APPNP (8 iters), h0 = H; ping-pong, last writes d_out ---
    float* dout = (float*)d_out;
    appnp_kernel<<<N_TOT, 128, 0, stream>>>(H,  Z1, H, a_rows, a_wts, a_off, dinv);
    appnp_kernel<<<N_TOT, 128, 0, stream>>>(Z1, Z2, H, a_rows, a_wts, a_off, dinv);
    appnp_kernel<<<N_TOT, 128, 0, stream>>>(Z2, Z1, H, a_rows, a_wts, a_off, dinv);
    appnp_kernel<<<N_TOT, 128, 0, stream>>>(Z1, Z2, H, a_rows, a_wts, a_off, dinv);
    appnp_kernel<<<N_TOT, 128, 0, stream>>>(Z2, Z1, H, a_rows, a_wts, a_off, dinv);
    appnp_kernel<<<N_TOT, 128, 0, stream>>>(Z1, Z2, H, a_rows, a_wts, a_off, dinv);
    appnp_kernel<<<N_TOT, 128, 0, stream>>>(Z2, Z1, H, a_rows, a_wts, a_off, dinv);
    appnp_kernel<<<N_TOT, 128, 0, stream>>>(Z1, dout, H, a_rows, a_wts, a_off, dinv);
}

// Round 3
// 1463.585 us; speedup vs baseline: 1.6528x; 1.6528x over previous
//
#include <hip/hip_runtime.h>

#define N_GENE 50000
#define N_PATH 20000
#define N_VACC 10000
#define N_TOT  80000
#define HID    128
#define E_PER  250000
#define OG 0
#define OP 50000
#define OV 70000

typedef __bf16 bf16x8 __attribute__((ext_vector_type(8)));
typedef __bf16 bf16x4 __attribute__((ext_vector_type(4)));
typedef float  f32x4  __attribute__((ext_vector_type(4)));

// segment layout of the concatenated count buffer:
// 0: appnp (N_TOT) | 1: rel0 (N_GENE) | 2: rel1 (N_PATH) | 3: rel2 (N_GENE) | 4: rel3 (N_GENE)
__constant__ int c_segn[5] = {N_TOT, N_GENE, N_PATH, N_GENE, N_GENE};
__constant__ int c_segb[5] = {0, 80000, 130000, 150000, 200000};
#define CNT_TOTAL 250000

struct Off5 { int* p[5]; };

// ---------------- CSR build ----------------

__global__ void count_kernel(const int* __restrict__ dst, int n, int* __restrict__ cnt, int doff)
{
    int e = blockIdx.x * 256 + threadIdx.x;
    if (e < n) atomicAdd(&cnt[dst[e] + doff], 1);
}

// 3-phase segmented exclusive scan; 4096 elems/block
__global__ void scan1_kernel(const int* __restrict__ cnt, int* __restrict__ partials)
{
    int seg = blockIdx.y, blk = blockIdx.x;
    int n = c_segn[seg];
    if (blk >= ((n + 4095) >> 12)) return;
    const int* base = cnt + c_segb[seg];
    int t = threadIdx.x;
    int i0 = (blk << 12) + t * 16;
    int s = 0;
#pragma unroll
    for (int j = 0; j < 16; j++) { int i = i0 + j; if (i < n) s += base[i]; }
    __shared__ int sh[256];
    sh[t] = s; __syncthreads();
    for (int d = 128; d; d >>= 1) { if (t < d) sh[t] += sh[t + d]; __syncthreads(); }
    if (t == 0) partials[seg * 32 + blk] = sh[0];
}

__global__ void scan2_kernel(int* __restrict__ partials, Off5 offs)
{
    int s = threadIdx.x;
    if (s < 5) {
        int n = c_segn[s];
        int nb = (n + 4095) >> 12;
        int run = 0;
        for (int b = 0; b < nb; b++) { int v = partials[s * 32 + b]; partials[s * 32 + b] = run; run += v; }
        offs.p[s][n] = run;  // sentinel
    }
}

__global__ void scan3_kernel(const int* __restrict__ cnt, const int* __restrict__ partials, Off5 offs)
{
    int seg = blockIdx.y, blk = blockIdx.x;
    int n = c_segn[seg];
    if (blk >= ((n + 4095) >> 12)) return;
    const int* base = cnt + c_segb[seg];
    int* off = offs.p[seg];
    int t = threadIdx.x;
    int i0 = (blk << 12) + t * 16;
    int loc[16];
    int s = 0;
#pragma unroll
    for (int j = 0; j < 16; j++) { int i = i0 + j; int v = (i < n) ? base[i] : 0; loc[j] = s; s += v; }
    __shared__ int sh[256];
    sh[t] = s; __syncthreads();
    for (int d = 1; d < 256; d <<= 1) {
        int v = (t >= d) ? sh[t - d] : 0; __syncthreads();
        sh[t] += v; __syncthreads();
    }
    int base_off = sh[t] - s + partials[seg * 32 + blk];
#pragma unroll
    for (int j = 0; j < 16; j++) { int i = i0 + j; if (i < n) off[i] = base_off + loc[j]; }
}

__global__ void dinv_kernel(const int* __restrict__ off, float* __restrict__ dinv, int n)
{
    int i = blockIdx.x * 256 + threadIdx.x;
    if (i < n) dinv[i] = rsqrtf((float)(off[i + 1] - off[i] + 1));  // +1 self loop
}

__global__ void fill_rel_kernel(const int* __restrict__ ei, int n,
                                const int* __restrict__ off, int* __restrict__ cur,
                                int* __restrict__ rows)
{
    int e = blockIdx.x * 256 + threadIdx.x;
    if (e < n) {
        int s = ei[e], d = ei[n + e];
        int pos = off[d] + atomicAdd(&cur[d], 1);
        rows[pos] = s;
    }
}

__global__ void fill_appnp_kernel(const int* __restrict__ ei, int n, int soff, int doff,
                                  const int* __restrict__ off, int* __restrict__ cur,
                                  int* __restrict__ rows, float* __restrict__ wts,
                                  const float* __restrict__ dinv)
{
    int e = blockIdx.x * 256 + threadIdx.x;
    if (e < n) {
        int s = ei[e] + soff, d = ei[n + e] + doff;
        int pos = off[d] + atomicAdd(&cur[d], 1);
        rows[pos] = s;
        wts[pos] = dinv[s];
    }
}

// ---------------- gather kernels (float4, 32 lanes/node, 8 nodes/block) ----------------

__global__ void agg_kernel(const float* __restrict__ hsrc, const int* __restrict__ rows,
                           const int* __restrict__ off, __bf16* __restrict__ out,
                           int ldo, int n_dst)
{
    int t = threadIdx.x;
    int node = blockIdx.x * 8 + (t >> 5);
    if (node >= n_dst) return;
    int sub = t & 31;
    int s = off[node], e = off[node + 1];
    f32x4 acc = {0.f, 0.f, 0.f, 0.f};
    for (int i = s; i < e; i++) {
        int r = rows[i];
        f32x4 v = *(const f32x4*)&hsrc[(size_t)r * HID + sub * 4];
        acc += v;
    }
    float inv = (e > s) ? 1.0f / (float)(e - s) : 0.0f;
    bf16x4 o;
    o[0] = (__bf16)(acc[0] * inv); o[1] = (__bf16)(acc[1] * inv);
    o[2] = (__bf16)(acc[2] * inv); o[3] = (__bf16)(acc[3] * inv);
    *(bf16x4*)&out[(size_t)node * ldo + sub * 4] = o;
}

__global__ void appnp_kernel(const float* __restrict__ zin, float* __restrict__ zout,
                             const float* __restrict__ h0,
                             const int* __restrict__ rows, const float* __restrict__ wts,
                             const int* __restrict__ off, const float* __restrict__ dinv)
{
    int t = threadIdx.x;
    int c = blockIdx.x * 8 + (t >> 5);
    int sub = t & 31;
    int s = off[c], e = off[c + 1];
    f32x4 acc = {0.f, 0.f, 0.f, 0.f};
    for (int i = s; i < e; i++) {
        float w = wts[i];
        int r = rows[i];
        f32x4 zv = *(const f32x4*)&zin[(size_t)r * HID + sub * 4];
        acc += zv * w;
    }
    float dc = dinv[c];
    size_t idx = (size_t)c * HID + sub * 4;
    f32x4 zi = *(const f32x4*)&zin[idx];
    f32x4 h = *(const f32x4*)&h0[idx];
    f32x4 res = (acc * dc + zi * (dc * dc)) * 0.9f + h * 0.1f;
    *(f32x4*)&zout[idx] = res;
}

// ---------------- weight prep ----------------

__global__ void cvtbf_kernel(const float* __restrict__ src, __bf16* __restrict__ dst, int n)
{
    int i = blockIdx.x * 256 + threadIdx.x;
    if (i < n) dst[i] = (__bf16)src[i];
}

// Wg: [128][512] = [WL0|WL2|WL3|WR0+WR2+WR3]; Wp: [128][256] = [WL1|WR1]
// bg = BL0+BL2+BL3; bp = BL1
__global__ void prep_sage_kernel(const float* __restrict__ wsl, const float* __restrict__ bsl,
                                 const float* __restrict__ wsr, int layer,
                                 __bf16* __restrict__ Wg, __bf16* __restrict__ Wp,
                                 float* __restrict__ bg, float* __restrict__ bp)
{
    int i = blockIdx.x * 256 + threadIdx.x;
    const float* WL = wsl + (size_t)layer * 4 * HID * HID;
    const float* WR = wsr + (size_t)layer * 4 * HID * HID;
    if (i < 128 * 512) {
        int nr = i >> 9, k = i & 511;
        float v;
        if (k < 128)      v = WL[0 * 16384 + nr * 128 + k];
        else if (k < 256) v = WL[2 * 16384 + nr * 128 + (k - 128)];
        else if (k < 384) v = WL[3 * 16384 + nr * 128 + (k - 256)];
        else {
            int kk = k - 384;
            v = WR[0 * 16384 + nr * 128 + kk] + WR[2 * 16384 + nr * 128 + kk] + WR[3 * 16384 + nr * 128 + kk];
        }
        Wg[i] = (__bf16)v;
    }
    if (i < 128 * 256) {
        int nr = i >> 8, k = i & 255;
        float v = (k < 128) ? WL[1 * 16384 + nr * 128 + k] : WR[1 * 16384 + nr * 128 + (k - 128)];
        Wp[i] = (__bf16)v;
    }
    if (i < 128) {
        const float* BL = bsl + (size_t)layer * 4 * HID;
        bg[i] = BL[0 * 128 + i] + BL[2 * 128 + i] + BL[3 * 128 + i];
        bp[i] = BL[1 * 128 + i];
    }
}

// ---------------- MFMA GEMMs ----------------
// layouts (verified r2, absmax 0.031): A[m=lane&15][k=quad*8+j]; B: n=lane&15 same k slice
// (row-major W contiguous); C/D: col=lane&15, row=quad*4+reg.

// input projection: H[M,128] = relu(X[M,K] @ W[128,K]^T + b)
template<int K>
__launch_bounds__(256)
__global__ void proj_kernel(const float* __restrict__ A, const __bf16* __restrict__ W,
                            const float* __restrict__ bias, float* __restrict__ OUT, int M)
{
    int wave = threadIdx.x >> 6, lane = threadIdx.x & 63;
    int m0 = (blockIdx.x * 4 + wave) * 16;
    if (m0 >= M) return;
    int r = lane & 15, quad = lane >> 4;
    f32x4 acc[8];
#pragma unroll
    for (int i = 0; i < 8; i++) acc[i] = (f32x4){0.f, 0.f, 0.f, 0.f};
    for (int k0 = 0; k0 < K; k0 += 32) {
        const float* ap = A + (size_t)(m0 + r) * K + k0 + quad * 8;
        f32x4 f0 = *(const f32x4*)ap;
        f32x4 f1 = *(const f32x4*)(ap + 4);
        bf16x8 a;
        a[0] = (__bf16)f0[0]; a[1] = (__bf16)f0[1]; a[2] = (__bf16)f0[2]; a[3] = (__bf16)f0[3];
        a[4] = (__bf16)f1[0]; a[5] = (__bf16)f1[1]; a[6] = (__bf16)f1[2]; a[7] = (__bf16)f1[3];
#pragma unroll
        for (int nt = 0; nt < 8; nt++) {
            bf16x8 b = *(const bf16x8*)(W + (size_t)(nt * 16 + r) * K + k0 + quad * 8);
            acc[nt] = __builtin_amdgcn_mfma_f32_16x16x32_bf16(a, b, acc[nt], 0, 0, 0);
        }
    }
#pragma unroll
    for (int nt = 0; nt < 8; nt++) {
        int n = nt * 16 + r;
        float bv = bias[n];
#pragma unroll
        for (int i = 0; i < 4; i++) {
            size_t idx = (size_t)(m0 + quad * 4 + i) * HID + n;
            OUT[idx] = fmaxf(acc[nt][i] + bv, 0.f);
        }
    }
}

// fused SAGE: H[M,128] = relu(H + scale*(concat(A1:bf16[M,K1], H:f32[M,128]) @ W[128,K1+128]^T + bias))
// in-place on H: each wave reads/writes only its own 16-row strip.
template<int K1>
__launch_bounds__(256)
__global__ void sage_gemm_kernel(const __bf16* __restrict__ A1, const __bf16* __restrict__ W,
                                 const float* __restrict__ bias, float scale,
                                 float* H, int M)
{
    constexpr int KT = K1 + 128;
    int wave = threadIdx.x >> 6, lane = threadIdx.x & 63;
    int m0 = (blockIdx.x * 4 + wave) * 16;
    if (m0 >= M) return;
    int r = lane & 15, quad = lane >> 4;
    f32x4 acc[8];
#pragma unroll
    for (int i = 0; i < 8; i++) acc[i] = (f32x4){0.f, 0.f, 0.f, 0.f};
#pragma unroll
    for (int k0 = 0; k0 < KT; k0 += 32) {
        bf16x8 a;
        if (k0 < K1) {
            a = *(const bf16x8*)(A1 + (size_t)(m0 + r) * K1 + k0 + quad * 8);
        } else {
            const float* ap = H + (size_t)(m0 + r) * HID + (k0 - K1) + quad * 8;
            f32x4 f0 = *(const f32x4*)ap;
            f32x4 f1 = *(const f32x4*)(ap + 4);
            a[0] = (__bf16)f0[0]; a[1] = (__bf16)f0[1]; a[2] = (__bf16)f0[2]; a[3] = (__bf16)f0[3];
            a[4] = (__bf16)f1[0]; a[5] = (__bf16)f1[1]; a[6] = (__bf16)f1[2]; a[7] = (__bf16)f1[3];
        }
#pragma unroll
        for (int nt = 0; nt < 8; nt++) {
            bf16x8 b = *(const bf16x8*)(W + (size_t)(nt * 16 + r) * KT + k0 + quad * 8);
            acc[nt] = __builtin_amdgcn_mfma_f32_16x16x32_bf16(a, b, acc[nt], 0, 0, 0);
        }
    }
#pragma unroll
    for (int nt = 0; nt < 8; nt++) {
        int n = nt * 16 + r;
        float bv = bias[n];
#pragma unroll
        for (int i = 0; i < 4; i++) {
            size_t idx = (size_t)(m0 + quad * 4 + i) * HID + n;
            float v = (acc[nt][i] + bv) * scale;
            H[idx] = fmaxf(H[idx] + v, 0.f);
        }
    }
}

// ---------------- driver ----------------

extern "C" void kernel_launch(void* const* d_in, const int* in_sizes, int n_in,
                              void* d_out, int out_size, void* d_ws, size_t ws_size,
                              hipStream_t stream)
{
    (void)in_sizes; (void)n_in; (void)out_size; (void)ws_size;

    const float* x_gene = (const float*)d_in[0];
    const float* x_path = (const float*)d_in[1];
    const float* x_vacc = (const float*)d_in[2];
    const float* win_g  = (const float*)d_in[3];
    const float* bin_g  = (const float*)d_in[4];
    const float* win_p  = (const float*)d_in[5];
    const float* bin_p  = (const float*)d_in[6];
    const float* win_v  = (const float*)d_in[7];
    const float* bin_v  = (const float*)d_in[8];
    const float* wsl    = (const float*)d_in[9];
    const float* bsl    = (const float*)d_in[10];
    const float* wsr    = (const float*)d_in[11];
    const int* ei_tg  = (const int*)d_in[12];  // vaccine -> gene
    const int* ei_ing = (const int*)d_in[13];  // gene -> pathway
    const int* ei_ct  = (const int*)d_in[14];  // pathway -> gene
    const int* ei_ii  = (const int*)d_in[15];  // gene -> gene

    char* p = (char*)d_ws;
    auto alloc = [&](size_t b) { char* r = p; p += (b + 255) & ~((size_t)255); return r; };

    float* H     = (float*)alloc((size_t)N_TOT * HID * 4);
    float* Z1    = (float*)alloc((size_t)N_TOT * HID * 4);
    float* Z2    = (float*)alloc((size_t)N_TOT * HID * 4);
    __bf16* AGG_G = (__bf16*)alloc((size_t)N_GENE * 384 * 2);
    __bf16* AGG_P = (__bf16*)alloc((size_t)N_PATH * 128 * 2);
    int*   a_rows = (int*)alloc((size_t)4 * E_PER * 4);
    float* a_wts  = (float*)alloc((size_t)4 * E_PER * 4);
    int*   a_off  = (int*)alloc((size_t)(N_TOT + 1) * 4);
    float* dinv   = (float*)alloc((size_t)N_TOT * 4);
    int* r_rows[4], *r_off[4];
    for (int r = 0; r < 4; r++) r_rows[r] = (int*)alloc((size_t)E_PER * 4);
    r_off[0] = (int*)alloc((size_t)(N_GENE + 1) * 4);
    r_off[1] = (int*)alloc((size_t)(N_PATH + 1) * 4);
    r_off[2] = (int*)alloc((size_t)(N_GENE + 1) * 4);
    r_off[3] = (int*)alloc((size_t)(N_GENE + 1) * 4);
    int* partials = (int*)alloc((size_t)5 * 32 * 4);
    // bf16/pre-summed weight shadows
    __bf16* wbf_g = (__bf16*)alloc((size_t)HID * 256 * 2);
    __bf16* wbf_p = (__bf16*)alloc((size_t)HID * 128 * 2);
    __bf16* wbf_v = (__bf16*)alloc((size_t)HID * 64 * 2);
    __bf16* Wg[2]; __bf16* Wp[2]; float* bg[2]; float* bp[2];
    for (int l = 0; l < 2; l++) {
        Wg[l] = (__bf16*)alloc((size_t)128 * 512 * 2);
        Wp[l] = (__bf16*)alloc((size_t)128 * 256 * 2);
        bg[l] = (float*)alloc(128 * 4);
        bp[l] = (float*)alloc(128 * 4);
    }
    // zero-init block
    char* zb = p;
    int* cnt = (int*)alloc((size_t)CNT_TOTAL * 4);
    int* cur = (int*)alloc((size_t)CNT_TOTAL * 4);
    hipMemsetAsync(zb, 0, (size_t)(p - zb), stream);

    Off5 offs;
    offs.p[0] = a_off; offs.p[1] = r_off[0]; offs.p[2] = r_off[1];
    offs.p[3] = r_off[2]; offs.p[4] = r_off[3];

    const int GE = (E_PER + 255) / 256;
    const int GB_G = (N_GENE / 16 + 3) / 4;
    const int GB_P = (N_PATH / 16 + 3) / 4;
    const int GB_V = (N_VACC / 16 + 3) / 4;

    // --- weight prep ---
    cvtbf_kernel<<<(HID * 256 + 255) / 256, 256, 0, stream>>>(win_g, wbf_g, HID * 256);
    cvtbf_kernel<<<(HID * 128 + 255) / 256, 256, 0, stream>>>(win_p, wbf_p, HID * 128);
    cvtbf_kernel<<<(HID * 64 + 255) / 256, 256, 0, stream>>>(win_v, wbf_v, HID * 64);
    prep_sage_kernel<<<256, 256, 0, stream>>>(wsl, bsl, wsr, 0, Wg[0], Wp[0], bg[0], bp[0]);
    prep_sage_kernel<<<256, 256, 0, stream>>>(wsl, bsl, wsr, 1, Wg[1], Wp[1], bg[1], bp[1]);

    // --- CSR counts ---
    count_kernel<<<GE, 256, 0, stream>>>(ei_tg + E_PER, E_PER, cnt, OG);
    count_kernel<<<GE, 256, 0, stream>>>(ei_ing + E_PER, E_PER, cnt, OP);
    count_kernel<<<GE, 256, 0, stream>>>(ei_ct + E_PER, E_PER, cnt, OG);
    count_kernel<<<GE, 256, 0, stream>>>(ei_ii + E_PER, E_PER, cnt, OG);
    count_kernel<<<GE, 256, 0, stream>>>(ei_tg + E_PER, E_PER, cnt + 80000, 0);
    count_kernel<<<GE, 256, 0, stream>>>(ei_ing + E_PER, E_PER, cnt + 130000, 0);
    count_kernel<<<GE, 256, 0, stream>>>(ei_ct + E_PER, E_PER, cnt + 150000, 0);
    count_kernel<<<GE, 256, 0, stream>>>(ei_ii + E_PER, E_PER, cnt + 200000, 0);

    // --- batched segmented scan ---
    dim3 sg((N_TOT + 4095) / 4096, 5);
    scan1_kernel<<<sg, 256, 0, stream>>>(cnt, partials);
    scan2_kernel<<<1, 64, 0, stream>>>(partials, offs);
    scan3_kernel<<<sg, 256, 0, stream>>>(cnt, partials, offs);

    dinv_kernel<<<(N_TOT + 255) / 256, 256, 0, stream>>>(a_off, dinv, N_TOT);

    fill_appnp_kernel<<<GE, 256, 0, stream>>>(ei_tg, E_PER, OV, OG, a_off, cur, a_rows, a_wts, dinv);
    fill_appnp_kernel<<<GE, 256, 0, stream>>>(ei_ing, E_PER, OG, OP, a_off, cur, a_rows, a_wts, dinv);
    fill_appnp_kernel<<<GE, 256, 0, stream>>>(ei_ct, E_PER, OP, OG, a_off, cur, a_rows, a_wts, dinv);
    fill_appnp_kernel<<<GE, 256, 0, stream>>>(ei_ii, E_PER, OG, OG, a_off, cur, a_rows, a_wts, dinv);
    fill_rel_kernel<<<GE, 256, 0, stream>>>(ei_tg, E_PER, r_off[0], cur + 80000, r_rows[0]);
    fill_rel_kernel<<<GE, 256, 0, stream>>>(ei_ing, E_PER, r_off[1], cur + 130000, r_rows[1]);
    fill_rel_kernel<<<GE, 256, 0, stream>>>(ei_ct, E_PER, r_off[2], cur + 150000, r_rows[2]);
    fill_rel_kernel<<<GE, 256, 0, stream>>>(ei_ii, E_PER, r_off[3], cur + 200000, r_rows[3]);

    // --- input projections (relu) ---
    proj_kernel<256><<<GB_G, 256, 0, stream>>>(x_gene, wbf_g, bin_g, H, N_GENE);
    proj_kernel<128><<<GB_P, 256, 0, stream>>>(x_path, wbf_p, bin_p, H + (size_t)OP * HID, N_PATH);
    proj_kernel< 64><<<GB_V, 256, 0, stream>>>(x_vacc, wbf_v, bin_v, H + (size_t)OV * HID, N_VACC);

    // --- 2 hetero-SAGE layers ---
    for (int l = 0; l < 2; l++) {
        // aggs (read old H)
        agg_kernel<<<N_GENE / 8, 256, 0, stream>>>(H + (size_t)OV * HID, r_rows[0], r_off[0], AGG_G + 0, 384, N_GENE);
        agg_kernel<<<N_GENE / 8, 256, 0, stream>>>(H + (size_t)OP * HID, r_rows[2], r_off[2], AGG_G + 128, 384, N_GENE);
        agg_kernel<<<N_GENE / 8, 256, 0, stream>>>(H, r_rows[3], r_off[3], AGG_G + 256, 384, N_GENE);
        agg_kernel<<<N_PATH / 8, 256, 0, stream>>>(H, r_rows[1], r_off[1], AGG_P, 128, N_PATH);
        // fused gene update (in-place H gene rows)
        sage_gemm_kernel<384><<<GB_G, 256, 0, stream>>>(AGG_G, Wg[l], bg[l], 1.0f / 3.0f, H, N_GENE);
        // fused pathway update (in-place H pathway rows)
        sage_gemm_kernel<128><<<GB_P, 256, 0, stream>>>(AGG_P, Wp[l], bp[l], 1.0f, H + (size_t)OP * HID, N_PATH);
        // vaccine: relu(hv) is idempotent (hv >= 0) -> no-op
    }

    // --- APPNP (8 iters), h0 = H; ping-pong, last writes d_out ---
    float* dout = (float*)d_out;
    appnp_kernel<<<N_TOT / 8, 256, 0, stream>>>(H,  Z1, H, a_rows, a_wts, a_off, dinv);
    appnp_kernel<<<N_TOT / 8, 256, 0, stream>>>(Z1, Z2, H, a_rows, a_wts, a_off, dinv);
    appnp_kernel<<<N_TOT / 8, 256, 0, stream>>>(Z2, Z1, H, a_rows, a_wts, a_off, dinv);
    appnp_kernel<<<N_TOT / 8, 256, 0, stream>>>(Z1, Z2, H, a_rows, a_wts, a_off, dinv);
    appnp_kernel<<<N_TOT / 8, 256, 0, stream>>>(Z2, Z1, H, a_rows, a_wts, a_off, dinv);
    appnp_kernel<<<N_TOT / 8, 256, 0, stream>>>(Z1, Z2, H, a_rows, a_wts, a_off, dinv);
    appnp_kernel<<<N_TOT / 8, 256, 0, stream>>>(Z2, Z1, H, a_rows, a_wts, a_off, dinv);
    appnp_kernel<<<N_TOT / 8, 256, 0, stream>>>(Z1, dout, H, a_rows, a_wts, a_off, dinv);
}

// Round 4
// 1068.880 us; speedup vs baseline: 2.2631x; 1.3693x over previous
//
#include <hip/hip_runtime.h>

#define N_GENE 50000
#define N_PATH 20000
#define N_VACC 10000
#define N_TOT  80000
#define HID    128
#define E_PER  250000
#define OG 0
#define OP 50000
#define OV 70000

typedef __bf16    bf16x8 __attribute__((ext_vector_type(8)));
typedef __bf16    bf16x4 __attribute__((ext_vector_type(4)));
typedef _Float16  f16x4  __attribute__((ext_vector_type(4)));
typedef float     f32x4  __attribute__((ext_vector_type(4)));

// count buffer layout (shared by cnt and cur):
// [0,80000): appnp (3 dynamic relations, global ids) | 80000: rel0 | 130000: rel1 | 150000: rel2 | 200000: rel3
__constant__ int c_segn[5] = {N_TOT, N_GENE, N_PATH, N_GENE, N_GENE};
__constant__ int c_segb[5] = {0, 80000, 130000, 150000, 200000};
#define CNT_TOTAL 250000

struct Off5 { int* p[5]; };
struct CntSeg { const int* dst; int* cnt; };   // cnt pre-offset by segment base + dst offset
struct Cnt7 { CntSeg s[7]; };
struct FillASeg { const int* ei; int soff; int doff; };
struct FillA3 { FillASeg s[3]; };
struct FillRSeg { const int* ei; const int* off; int* cur; int* rows; };
struct FillR4 { FillRSeg s[4]; };

// ---------------- CSR build ----------------

__global__ void count_all_kernel(Cnt7 a)
{
    int seg = blockIdx.y;
    int e = blockIdx.x * 256 + threadIdx.x;
    if (e < E_PER) atomicAdd(&a.s[seg].cnt[a.s[seg].dst[e]], 1);
}

// 3-phase segmented exclusive scan; 4096 elems/block
__global__ void scan1_kernel(const int* __restrict__ cnt, int* __restrict__ partials)
{
    int seg = blockIdx.y, blk = blockIdx.x;
    int n = c_segn[seg];
    if (blk >= ((n + 4095) >> 12)) return;
    const int* base = cnt + c_segb[seg];
    int t = threadIdx.x;
    int i0 = (blk << 12) + t * 16;
    int s = 0;
#pragma unroll
    for (int j = 0; j < 16; j++) { int i = i0 + j; if (i < n) s += base[i]; }
    __shared__ int sh[256];
    sh[t] = s; __syncthreads();
    for (int d = 128; d; d >>= 1) { if (t < d) sh[t] += sh[t + d]; __syncthreads(); }
    if (t == 0) partials[seg * 32 + blk] = sh[0];
}

__global__ void scan2_kernel(int* __restrict__ partials, Off5 offs)
{
    int s = threadIdx.x;
    if (s < 5) {
        int n = c_segn[s];
        int nb = (n + 4095) >> 12;
        int run = 0;
        for (int b = 0; b < nb; b++) { int v = partials[s * 32 + b]; partials[s * 32 + b] = run; run += v; }
        offs.p[s][n] = run;  // sentinel
    }
}

__global__ void scan3_kernel(const int* __restrict__ cnt, const int* __restrict__ partials, Off5 offs)
{
    int seg = blockIdx.y, blk = blockIdx.x;
    int n = c_segn[seg];
    if (blk >= ((n + 4095) >> 12)) return;
    const int* base = cnt + c_segb[seg];
    int* off = offs.p[seg];
    int t = threadIdx.x;
    int i0 = (blk << 12) + t * 16;
    int loc[16];
    int s = 0;
#pragma unroll
    for (int j = 0; j < 16; j++) { int i = i0 + j; int v = (i < n) ? base[i] : 0; loc[j] = s; s += v; }
    __shared__ int sh[256];
    sh[t] = s; __syncthreads();
    for (int d = 1; d < 256; d <<= 1) {
        int v = (t >= d) ? sh[t - d] : 0; __syncthreads();
        sh[t] += v; __syncthreads();
    }
    int base_off = sh[t] - s + partials[seg * 32 + blk];
#pragma unroll
    for (int j = 0; j < 16; j++) { int i = i0 + j; if (i < n) off[i] = base_off + loc[j]; }
}

// degree = appnp-dynamic in-edges + (genes: targets in-edges) + 1 self-loop
__global__ void dinv_kernel(const int* __restrict__ a_off, const int* __restrict__ r0off,
                            float* __restrict__ dinv)
{
    int i = blockIdx.x * 256 + threadIdx.x;
    if (i >= N_TOT) return;
    int deg = a_off[i + 1] - a_off[i] + 1;
    if (i < N_GENE) deg += r0off[i + 1] - r0off[i];
    dinv[i] = rsqrtf((float)deg);
}

__global__ void fill_appnp_kernel(FillA3 a, const int* __restrict__ off, int* __restrict__ cur,
                                  int* __restrict__ rows, float* __restrict__ wts,
                                  const float* __restrict__ dinv)
{
    int seg = blockIdx.y;
    int e = blockIdx.x * 256 + threadIdx.x;
    if (e >= E_PER) return;
    const int* ei = a.s[seg].ei;
    int s = ei[e] + a.s[seg].soff, d = ei[E_PER + e] + a.s[seg].doff;
    int pos = off[d] + atomicAdd(&cur[d], 1);
    rows[pos] = s;
    wts[pos] = dinv[s];
}

__global__ void fill_rel_kernel(FillR4 a)
{
    int seg = blockIdx.y;
    int e = blockIdx.x * 256 + threadIdx.x;
    if (e >= E_PER) return;
    const int* ei = a.s[seg].ei;
    int s = ei[e], d = ei[E_PER + e];
    int pos = a.s[seg].off[d] + atomicAdd(&a.s[seg].cur[d], 1);
    a.s[seg].rows[pos] = s;
}

// ---------------- gather kernels (32 lanes/node, 8 nodes/block) ----------------

__global__ void agg_kernel(const __bf16* __restrict__ hsrc, const int* __restrict__ rows,
                           const int* __restrict__ off, __bf16* __restrict__ out,
                           int ldo, int n_dst)
{
    int t = threadIdx.x;
    int node = blockIdx.x * 8 + (t >> 5);
    if (node >= n_dst) return;
    int sub = t & 31;
    int s = off[node], e = off[node + 1];
    f32x4 acc0 = {0.f, 0.f, 0.f, 0.f}, acc1 = {0.f, 0.f, 0.f, 0.f};
    int i = s;
    for (; i + 2 <= e; i += 2) {
        int r0 = rows[i], r1 = rows[i + 1];
        bf16x4 a = *(const bf16x4*)&hsrc[(size_t)r0 * HID + sub * 4];
        bf16x4 b = *(const bf16x4*)&hsrc[(size_t)r1 * HID + sub * 4];
        acc0[0] += (float)a[0]; acc0[1] += (float)a[1]; acc0[2] += (float)a[2]; acc0[3] += (float)a[3];
        acc1[0] += (float)b[0]; acc1[1] += (float)b[1]; acc1[2] += (float)b[2]; acc1[3] += (float)b[3];
    }
    if (i < e) {
        bf16x4 a = *(const bf16x4*)&hsrc[(size_t)rows[i] * HID + sub * 4];
        acc0[0] += (float)a[0]; acc0[1] += (float)a[1]; acc0[2] += (float)a[2]; acc0[3] += (float)a[3];
    }
    f32x4 acc = acc0 + acc1;
    float inv = (e > s) ? 1.0f / (float)(e - s) : 0.0f;
    bf16x4 o;
    o[0] = (__bf16)(acc[0] * inv); o[1] = (__bf16)(acc[1] * inv);
    o[2] = (__bf16)(acc[2] * inv); o[3] = (__bf16)(acc[3] * inv);
    *(bf16x4*)&out[(size_t)node * ldo + sub * 4] = o;
}

// base = 0.1*H + (genes: 0.9*dinv*sum_{v->g} h_v); z0 = fp16(H)
__global__ void base_kernel(const float* __restrict__ H, const int* __restrict__ r0rows,
                            const int* __restrict__ r0off, const float* __restrict__ dinv,
                            float* __restrict__ base, _Float16* __restrict__ z0)
{
    int t = threadIdx.x;
    int node = blockIdx.x * 8 + (t >> 5);
    int sub = t & 31;
    size_t idx = (size_t)node * HID + sub * 4;
    f32x4 h = *(const f32x4*)&H[idx];
    f32x4 acc = {0.f, 0.f, 0.f, 0.f};
    if (node < N_GENE) {
        for (int i = r0off[node]; i < r0off[node + 1]; i++) {
            acc += *(const f32x4*)&H[(size_t)(OV + r0rows[i]) * HID + sub * 4];
        }
        acc *= 0.9f * dinv[node];
    }
    f32x4 b = h * 0.1f + acc;
    *(f32x4*)&base[idx] = b;
    f16x4 z;
    z[0] = (_Float16)h[0]; z[1] = (_Float16)h[1]; z[2] = (_Float16)h[2]; z[3] = (_Float16)h[3];
    *(f16x4*)&z0[idx] = z;
}

template<typename OT>
__launch_bounds__(256)
__global__ void appnp_kernel(const _Float16* __restrict__ zin, OT* __restrict__ zout,
                             const float* __restrict__ base,
                             const int* __restrict__ rows, const float* __restrict__ wts,
                             const int* __restrict__ off, const float* __restrict__ dinv)
{
    int t = threadIdx.x;
    int c = blockIdx.x * 8 + (t >> 5);
    int sub = t & 31;
    int s = off[c], e = off[c + 1];
    f32x4 acc0 = {0.f, 0.f, 0.f, 0.f}, acc1 = {0.f, 0.f, 0.f, 0.f};
    int i = s;
    for (; i + 2 <= e; i += 2) {
        int r0 = rows[i], r1 = rows[i + 1];
        float w0 = wts[i], w1 = wts[i + 1];
        f16x4 a = *(const f16x4*)&zin[(size_t)r0 * HID + sub * 4];
        f16x4 b = *(const f16x4*)&zin[(size_t)r1 * HID + sub * 4];
        acc0[0] += (float)a[0] * w0; acc0[1] += (float)a[1] * w0;
        acc0[2] += (float)a[2] * w0; acc0[3] += (float)a[3] * w0;
        acc1[0] += (float)b[0] * w1; acc1[1] += (float)b[1] * w1;
        acc1[2] += (float)b[2] * w1; acc1[3] += (float)b[3] * w1;
    }
    if (i < e) {
        float w0 = wts[i];
        f16x4 a = *(const f16x4*)&zin[(size_t)rows[i] * HID + sub * 4];
        acc0[0] += (float)a[0] * w0; acc0[1] += (float)a[1] * w0;
        acc0[2] += (float)a[2] * w0; acc0[3] += (float)a[3] * w0;
    }
    f32x4 acc = acc0 + acc1;
    float dc = dinv[c];
    size_t idx = (size_t)c * HID + sub * 4;
    f16x4 zi = *(const f16x4*)&zin[idx];
    f32x4 bs = *(const f32x4*)&base[idx];
    f32x4 res;
    float d2 = dc * dc;
#pragma unroll
    for (int j = 0; j < 4; j++) res[j] = 0.9f * (dc * acc[j] + d2 * (float)zi[j]) + bs[j];
    if constexpr (sizeof(OT) == 2) {
        f16x4 o;
        o[0] = (_Float16)res[0]; o[1] = (_Float16)res[1]; o[2] = (_Float16)res[2]; o[3] = (_Float16)res[3];
        *(f16x4*)&zout[idx] = o;
    } else {
        *(f32x4*)&zout[idx] = res;
    }
}

// ---------------- weight prep ----------------

__global__ void cvtbf_kernel(const float* __restrict__ src, __bf16* __restrict__ dst, int n)
{
    int i = blockIdx.x * 256 + threadIdx.x;
    if (i < n) dst[i] = (__bf16)src[i];
}

// Wg: [128][512] = [WL0|WL2|WL3|WR0+WR2+WR3]; Wp: [128][256] = [WL1|WR1]
__global__ void prep_sage_kernel(const float* __restrict__ wsl, const float* __restrict__ bsl,
                                 const float* __restrict__ wsr, int layer,
                                 __bf16* __restrict__ Wg, __bf16* __restrict__ Wp,
                                 float* __restrict__ bg, float* __restrict__ bp)
{
    int i = blockIdx.x * 256 + threadIdx.x;
    const float* WL = wsl + (size_t)layer * 4 * HID * HID;
    const float* WR = wsr + (size_t)layer * 4 * HID * HID;
    if (i < 128 * 512) {
        int nr = i >> 9, k = i & 511;
        float v;
        if (k < 128)      v = WL[0 * 16384 + nr * 128 + k];
        else if (k < 256) v = WL[2 * 16384 + nr * 128 + (k - 128)];
        else if (k < 384) v = WL[3 * 16384 + nr * 128 + (k - 256)];
        else {
            int kk = k - 384;
            v = WR[0 * 16384 + nr * 128 + kk] + WR[2 * 16384 + nr * 128 + kk] + WR[3 * 16384 + nr * 128 + kk];
        }
        Wg[i] = (__bf16)v;
    }
    if (i < 128 * 256) {
        int nr = i >> 8, k = i & 255;
        float v = (k < 128) ? WL[1 * 16384 + nr * 128 + k] : WR[1 * 16384 + nr * 128 + (k - 128)];
        Wp[i] = (__bf16)v;
    }
    if (i < 128) {
        const float* BL = bsl + (size_t)layer * 4 * HID;
        bg[i] = BL[0 * 128 + i] + BL[2 * 128 + i] + BL[3 * 128 + i];
        bp[i] = BL[1 * 128 + i];
    }
}

// ---------------- MFMA GEMMs ----------------
// verified layouts: A[m=lane&15][k=quad*8+j]; B: n=lane&15, same k slice; C/D: col=lane&15, row=quad*4+reg.

template<int K>
__launch_bounds__(256)
__global__ void proj_kernel(const float* __restrict__ A, const __bf16* __restrict__ W,
                            const float* __restrict__ bias, float* __restrict__ OUT,
                            __bf16* __restrict__ OUTBF, int M)
{
    int wave = threadIdx.x >> 6, lane = threadIdx.x & 63;
    int m0 = (blockIdx.x * 4 + wave) * 16;
    if (m0 >= M) return;
    int r = lane & 15, quad = lane >> 4;
    f32x4 acc[8];
#pragma unroll
    for (int i = 0; i < 8; i++) acc[i] = (f32x4){0.f, 0.f, 0.f, 0.f};
    for (int k0 = 0; k0 < K; k0 += 32) {
        const float* ap = A + (size_t)(m0 + r) * K + k0 + quad * 8;
        f32x4 f0 = *(const f32x4*)ap;
        f32x4 f1 = *(const f32x4*)(ap + 4);
        bf16x8 a;
        a[0] = (__bf16)f0[0]; a[1] = (__bf16)f0[1]; a[2] = (__bf16)f0[2]; a[3] = (__bf16)f0[3];
        a[4] = (__bf16)f1[0]; a[5] = (__bf16)f1[1]; a[6] = (__bf16)f1[2]; a[7] = (__bf16)f1[3];
#pragma unroll
        for (int nt = 0; nt < 8; nt++) {
            bf16x8 b = *(const bf16x8*)(W + (size_t)(nt * 16 + r) * K + k0 + quad * 8);
            acc[nt] = __builtin_amdgcn_mfma_f32_16x16x32_bf16(a, b, acc[nt], 0, 0, 0);
        }
    }
#pragma unroll
    for (int nt = 0; nt < 8; nt++) {
        int n = nt * 16 + r;
        float bv = bias[n];
#pragma unroll
        for (int i = 0; i < 4; i++) {
            size_t idx = (size_t)(m0 + quad * 4 + i) * HID + n;
            float v = fmaxf(acc[nt][i] + bv, 0.f);
            OUT[idx] = v;
            OUTBF[idx] = (__bf16)v;
        }
    }
}

// fused SAGE: H = relu(H + scale*(concat(A1 bf16[M,K1], Hbf[M,128]) @ W^T + bias)), updates Hbf too
template<int K1>
__launch_bounds__(256)
__global__ void sage_gemm_kernel(const __bf16* __restrict__ A1, const __bf16* __restrict__ W,
                                 const float* __restrict__ bias, float scale,
                                 float* H, __bf16* Hbf, int M)
{
    constexpr int KT = K1 + 128;
    int wave = threadIdx.x >> 6, lane = threadIdx.x & 63;
    int m0 = (blockIdx.x * 4 + wave) * 16;
    if (m0 >= M) return;
    int r = lane & 15, quad = lane >> 4;
    f32x4 acc[8];
#pragma unroll
    for (int i = 0; i < 8; i++) acc[i] = (f32x4){0.f, 0.f, 0.f, 0.f};
#pragma unroll
    for (int k0 = 0; k0 < KT; k0 += 32) {
        bf16x8 a;
        if (k0 < K1) a = *(const bf16x8*)(A1 + (size_t)(m0 + r) * K1 + k0 + quad * 8);
        else         a = *(const bf16x8*)(Hbf + (size_t)(m0 + r) * HID + (k0 - K1) + quad * 8);
#pragma unroll
        for (int nt = 0; nt < 8; nt++) {
            bf16x8 b = *(const bf16x8*)(W + (size_t)(nt * 16 + r) * KT + k0 + quad * 8);
            acc[nt] = __builtin_amdgcn_mfma_f32_16x16x32_bf16(a, b, acc[nt], 0, 0, 0);
        }
    }
#pragma unroll
    for (int nt = 0; nt < 8; nt++) {
        int n = nt * 16 + r;
        float bv = bias[n];
#pragma unroll
        for (int i = 0; i < 4; i++) {
            size_t idx = (size_t)(m0 + quad * 4 + i) * HID + n;
            float v = fmaxf(H[idx] + (acc[nt][i] + bv) * scale, 0.f);
            H[idx] = v;
            Hbf[idx] = (__bf16)v;
        }
    }
}

// ---------------- driver ----------------

extern "C" void kernel_launch(void* const* d_in, const int* in_sizes, int n_in,
                              void* d_out, int out_size, void* d_ws, size_t ws_size,
                              hipStream_t stream)
{
    (void)in_sizes; (void)n_in; (void)out_size; (void)ws_size;

    const float* x_gene = (const float*)d_in[0];
    const float* x_path = (const float*)d_in[1];
    const float* x_vacc = (const float*)d_in[2];
    const float* win_g  = (const float*)d_in[3];
    const float* bin_g  = (const float*)d_in[4];
    const float* win_p  = (const float*)d_in[5];
    const float* bin_p  = (const float*)d_in[6];
    const float* win_v  = (const float*)d_in[7];
    const float* bin_v  = (const float*)d_in[8];
    const float* wsl    = (const float*)d_in[9];
    const float* bsl    = (const float*)d_in[10];
    const float* wsr    = (const float*)d_in[11];
    const int* ei_tg  = (const int*)d_in[12];  // vaccine -> gene
    const int* ei_ing = (const int*)d_in[13];  // gene -> pathway
    const int* ei_ct  = (const int*)d_in[14];  // pathway -> gene
    const int* ei_ii  = (const int*)d_in[15];  // gene -> gene

    char* p = (char*)d_ws;
    auto alloc = [&](size_t b) { char* r = p; p += (b + 255) & ~((size_t)255); return r; };

    float*    H    = (float*)alloc((size_t)N_TOT * HID * 4);
    float*    BASE = (float*)alloc((size_t)N_TOT * HID * 4);
    __bf16*   Hbf  = (__bf16*)alloc((size_t)N_TOT * HID * 2);
    _Float16* Z1   = (_Float16*)alloc((size_t)N_TOT * HID * 2);
    _Float16* Z2   = (_Float16*)alloc((size_t)N_TOT * HID * 2);
    __bf16* AGG_G = (__bf16*)alloc((size_t)N_GENE * 384 * 2);
    __bf16* AGG_P = (__bf16*)alloc((size_t)N_PATH * 128 * 2);
    int*   a_rows = (int*)alloc((size_t)3 * E_PER * 4);
    float* a_wts  = (float*)alloc((size_t)3 * E_PER * 4);
    int*   a_off  = (int*)alloc((size_t)(N_TOT + 1) * 4);
    float* dinv   = (float*)alloc((size_t)N_TOT * 4);
    int* r_rows[4], *r_off[4];
    for (int r = 0; r < 4; r++) r_rows[r] = (int*)alloc((size_t)E_PER * 4);
    r_off[0] = (int*)alloc((size_t)(N_GENE + 1) * 4);
    r_off[1] = (int*)alloc((size_t)(N_PATH + 1) * 4);
    r_off[2] = (int*)alloc((size_t)(N_GENE + 1) * 4);
    r_off[3] = (int*)alloc((size_t)(N_GENE + 1) * 4);
    int* partials = (int*)alloc((size_t)5 * 32 * 4);
    __bf16* wbf_g = (__bf16*)alloc((size_t)HID * 256 * 2);
    __bf16* wbf_p = (__bf16*)alloc((size_t)HID * 128 * 2);
    __bf16* wbf_v = (__bf16*)alloc((size_t)HID * 64 * 2);
    __bf16* Wg[2]; __bf16* Wp[2]; float* bg[2]; float* bp[2];
    for (int l = 0; l < 2; l++) {
        Wg[l] = (__bf16*)alloc((size_t)128 * 512 * 2);
        Wp[l] = (__bf16*)alloc((size_t)128 * 256 * 2);
        bg[l] = (float*)alloc(128 * 4);
        bp[l] = (float*)alloc(128 * 4);
    }
    // zero-init block
    char* zb = p;
    int* cnt = (int*)alloc((size_t)CNT_TOTAL * 4);
    int* cur = (int*)alloc((size_t)CNT_TOTAL * 4);
    hipMemsetAsync(zb, 0, (size_t)(p - zb), stream);

    Off5 offs;
    offs.p[0] = a_off; offs.p[1] = r_off[0]; offs.p[2] = r_off[1];
    offs.p[3] = r_off[2]; offs.p[4] = r_off[3];

    const int GE = (E_PER + 255) / 256;
    const int GB_G = (N_GENE / 16 + 3) / 4;
    const int GB_P = (N_PATH / 16 + 3) / 4;
    const int GB_V = (N_VACC / 16 + 3) / 4;

    // --- weight prep ---
    cvtbf_kernel<<<(HID * 256 + 255) / 256, 256, 0, stream>>>(win_g, wbf_g, HID * 256);
    cvtbf_kernel<<<(HID * 128 + 255) / 256, 256, 0, stream>>>(win_p, wbf_p, HID * 128);
    cvtbf_kernel<<<(HID * 64 + 255) / 256, 256, 0, stream>>>(win_v, wbf_v, HID * 64);
    prep_sage_kernel<<<256, 256, 0, stream>>>(wsl, bsl, wsr, 0, Wg[0], Wp[0], bg[0], bp[0]);
    prep_sage_kernel<<<256, 256, 0, stream>>>(wsl, bsl, wsr, 1, Wg[1], Wp[1], bg[1], bp[1]);

    // --- CSR counts (merged): 3 appnp-dynamic + 4 per-relation ---
    Cnt7 c7;
    c7.s[0] = {ei_ing + E_PER, cnt + OP};      // gene->pathway, global dst
    c7.s[1] = {ei_ct + E_PER,  cnt + OG};      // pathway->gene
    c7.s[2] = {ei_ii + E_PER,  cnt + OG};      // gene->gene
    c7.s[3] = {ei_tg + E_PER,  cnt + 80000};   // rel0 local
    c7.s[4] = {ei_ing + E_PER, cnt + 130000};
    c7.s[5] = {ei_ct + E_PER,  cnt + 150000};
    c7.s[6] = {ei_ii + E_PER,  cnt + 200000};
    count_all_kernel<<<dim3(GE, 7), 256, 0, stream>>>(c7);

    dim3 sg((N_TOT + 4095) / 4096, 5);
    scan1_kernel<<<sg, 256, 0, stream>>>(cnt, partials);
    scan2_kernel<<<1, 64, 0, stream>>>(partials, offs);
    scan3_kernel<<<sg, 256, 0, stream>>>(cnt, partials, offs);

    dinv_kernel<<<(N_TOT + 255) / 256, 256, 0, stream>>>(a_off, r_off[0], dinv);

    FillA3 fa;
    fa.s[0] = {ei_ing, OG, OP};
    fa.s[1] = {ei_ct,  OP, OG};
    fa.s[2] = {ei_ii,  OG, OG};
    fill_appnp_kernel<<<dim3(GE, 3), 256, 0, stream>>>(fa, a_off, cur, a_rows, a_wts, dinv);
    FillR4 fr;
    fr.s[0] = {ei_tg,  r_off[0], cur + 80000,  r_rows[0]};
    fr.s[1] = {ei_ing, r_off[1], cur + 130000, r_rows[1]};
    fr.s[2] = {ei_ct,  r_off[2], cur + 150000, r_rows[2]};
    fr.s[3] = {ei_ii,  r_off[3], cur + 200000, r_rows[3]};
    fill_rel_kernel<<<dim3(GE, 4), 256, 0, stream>>>(fr);

    // --- input projections (relu) ---
    proj_kernel<256><<<GB_G, 256, 0, stream>>>(x_gene, wbf_g, bin_g, H, Hbf, N_GENE);
    proj_kernel<128><<<GB_P, 256, 0, stream>>>(x_path, wbf_p, bin_p, H + (size_t)OP * HID, Hbf + (size_t)OP * HID, N_PATH);
    proj_kernel< 64><<<GB_V, 256, 0, stream>>>(x_vacc, wbf_v, bin_v, H + (size_t)OV * HID, Hbf + (size_t)OV * HID, N_VACC);

    // --- 2 hetero-SAGE layers ---
    for (int l = 0; l < 2; l++) {
        agg_kernel<<<N_GENE / 8, 256, 0, stream>>>(Hbf + (size_t)OV * HID, r_rows[0], r_off[0], AGG_G + 0, 384, N_GENE);
        agg_kernel<<<N_GENE / 8, 256, 0, stream>>>(Hbf + (size_t)OP * HID, r_rows[2], r_off[2], AGG_G + 128, 384, N_GENE);
        agg_kernel<<<N_GENE / 8, 256, 0, stream>>>(Hbf, r_rows[3], r_off[3], AGG_G + 256, 384, N_GENE);
        agg_kernel<<<N_PATH / 8, 256, 0, stream>>>(Hbf, r_rows[1], r_off[1], AGG_P, 128, N_PATH);
        sage_gemm_kernel<384><<<GB_G, 256, 0, stream>>>(AGG_G, Wg[l], bg[l], 1.0f / 3.0f, H, Hbf, N_GENE);
        sage_gemm_kernel<128><<<GB_P, 256, 0, stream>>>(AGG_P, Wp[l], bp[l], 1.0f,
                                                        H + (size_t)OP * HID, Hbf + (size_t)OP * HID, N_PATH);
    }

    // --- APPNP: base + z0, then 8 gather iters (vaccine edges folded into base) ---
    base_kernel<<<N_TOT / 8, 256, 0, stream>>>(H, r_rows[0], r_off[0], dinv, BASE, Z1);

    float* dout = (float*)d_out;
    appnp_kernel<<<N_TOT / 8, 256, 0, stream>>>(Z1, Z2, BASE, a_rows, a_wts, a_off, dinv);
    appnp_kernel<<<N_TOT / 8, 256, 0, stream>>>(Z2, Z1, BASE, a_rows, a_wts, a_off, dinv);
    appnp_kernel<<<N_TOT / 8, 256, 0, stream>>>(Z1, Z2, BASE, a_rows, a_wts, a_off, dinv);
    appnp_kernel<<<N_TOT / 8, 256, 0, stream>>>(Z2, Z1, BASE, a_rows, a_wts, a_off, dinv);
    appnp_kernel<<<N_TOT / 8, 256, 0, stream>>>(Z1, Z2, BASE, a_rows, a_wts, a_off, dinv);
    appnp_kernel<<<N_TOT / 8, 256, 0, stream>>>(Z2, Z1, BASE, a_rows, a_wts, a_off, dinv);
    appnp_kernel<<<N_TOT / 8, 256, 0, stream>>>(Z1, Z2, BASE, a_rows, a_wts, a_off, dinv);
    appnp_kernel<<<N_TOT / 8, 256, 0, stream>>>(Z2, dout, BASE, a_rows, a_wts, a_off, dinv);
}

// Round 5
// 939.373 us; speedup vs baseline: 2.5751x; 1.1379x over previous
//
#include <hip/hip_runtime.h>

#define N_GENE 50000
#define N_PATH 20000
#define N_VACC 10000
#define N_TOT  80000
#define HID    128
#define E_PER  250000
#define OG 0
#define OP 50000
#define OV 70000

typedef __bf16    bf16x8 __attribute__((ext_vector_type(8)));
typedef __bf16    bf16x4 __attribute__((ext_vector_type(4)));
typedef _Float16  f16x4  __attribute__((ext_vector_type(4)));
typedef float     f32x4  __attribute__((ext_vector_type(4)));

__constant__ int c_segn[5] = {N_TOT, N_GENE, N_PATH, N_GENE, N_GENE};
__constant__ int c_segb[5] = {0, 80000, 130000, 150000, 200000};
#define CNT_TOTAL 250000

struct Off5 { int* p[5]; };
struct CntSeg { const int* dst; int* cnt; };
struct Cnt7 { CntSeg s[7]; };
struct FillASeg { const int* ei; int soff; int doff; };
struct FillA3 { FillASeg s[3]; };
struct FillRSeg { const int* ei; const int* off; int* cur; int* rows; };
struct FillR4 { FillRSeg s[4]; };
struct AggSeg { const __bf16* hsrc; const int* rows; const int* off; __bf16* out; int ldo; int n; };
struct Agg4 { AggSeg s[4]; };

// ---------------- CSR build ----------------

__global__ void count_all_kernel(Cnt7 a)
{
    int seg = blockIdx.y;
    int e = blockIdx.x * 256 + threadIdx.x;
    if (e < E_PER) atomicAdd(&a.s[seg].cnt[a.s[seg].dst[e]], 1);
}

__global__ void scan1_kernel(const int* __restrict__ cnt, int* __restrict__ partials)
{
    int seg = blockIdx.y, blk = blockIdx.x;
    int n = c_segn[seg];
    if (blk >= ((n + 4095) >> 12)) return;
    const int* base = cnt + c_segb[seg];
    int t = threadIdx.x;
    int i0 = (blk << 12) + t * 16;
    int s = 0;
#pragma unroll
    for (int j = 0; j < 16; j++) { int i = i0 + j; if (i < n) s += base[i]; }
    __shared__ int sh[256];
    sh[t] = s; __syncthreads();
    for (int d = 128; d; d >>= 1) { if (t < d) sh[t] += sh[t + d]; __syncthreads(); }
    if (t == 0) partials[seg * 32 + blk] = sh[0];
}

__global__ void scan2_kernel(int* __restrict__ partials, Off5 offs)
{
    int s = threadIdx.x;
    if (s < 5) {
        int n = c_segn[s];
        int nb = (n + 4095) >> 12;
        int run = 0;
        for (int b = 0; b < nb; b++) { int v = partials[s * 32 + b]; partials[s * 32 + b] = run; run += v; }
        offs.p[s][n] = run;
    }
}

__global__ void scan3_kernel(const int* __restrict__ cnt, const int* __restrict__ partials, Off5 offs)
{
    int seg = blockIdx.y, blk = blockIdx.x;
    int n = c_segn[seg];
    if (blk >= ((n + 4095) >> 12)) return;
    const int* base = cnt + c_segb[seg];
    int* off = offs.p[seg];
    int t = threadIdx.x;
    int i0 = (blk << 12) + t * 16;
    int loc[16];
    int s = 0;
#pragma unroll
    for (int j = 0; j < 16; j++) { int i = i0 + j; int v = (i < n) ? base[i] : 0; loc[j] = s; s += v; }
    __shared__ int sh[256];
    sh[t] = s; __syncthreads();
    for (int d = 1; d < 256; d <<= 1) {
        int v = (t >= d) ? sh[t - d] : 0; __syncthreads();
        sh[t] += v; __syncthreads();
    }
    int base_off = sh[t] - s + partials[seg * 32 + blk];
#pragma unroll
    for (int j = 0; j < 16; j++) { int i = i0 + j; if (i < n) off[i] = base_off + loc[j]; }
}

__global__ void dinv_kernel(const int* __restrict__ a_off, const int* __restrict__ r0off,
                            float* __restrict__ dinv)
{
    int i = blockIdx.x * 256 + threadIdx.x;
    if (i >= N_TOT) return;
    int deg = a_off[i + 1] - a_off[i] + 1;
    if (i < N_GENE) deg += r0off[i + 1] - r0off[i];
    dinv[i] = rsqrtf((float)deg);
}

__global__ void fill_appnp_kernel(FillA3 a, const int* __restrict__ off, int* __restrict__ cur,
                                  int* __restrict__ rows, float* __restrict__ wts,
                                  const float* __restrict__ dinv)
{
    int seg = blockIdx.y;
    int e = blockIdx.x * 256 + threadIdx.x;
    if (e >= E_PER) return;
    const int* ei = a.s[seg].ei;
    int s = ei[e] + a.s[seg].soff, d = ei[E_PER + e] + a.s[seg].doff;
    int pos = off[d] + atomicAdd(&cur[d], 1);
    rows[pos] = s;
    wts[pos] = dinv[s];
}

__global__ void fill_rel_kernel(FillR4 a)
{
    int seg = blockIdx.y;
    int e = blockIdx.x * 256 + threadIdx.x;
    if (e >= E_PER) return;
    const int* ei = a.s[seg].ei;
    int s = ei[e], d = ei[E_PER + e];
    int pos = a.s[seg].off[d] + atomicAdd(&a.s[seg].cur[d], 1);
    a.s[seg].rows[pos] = s;
}

// ---------------- gather kernels ----------------

__global__ void agg_all_kernel(Agg4 a)
{
    int seg = blockIdx.y;
    int t = threadIdx.x;
    int node = blockIdx.x * 8 + (t >> 5);
    if (node >= a.s[seg].n) return;
    const __bf16* hsrc = a.s[seg].hsrc;
    const int* rows = a.s[seg].rows;
    int sub = t & 31;
    int s = a.s[seg].off[node], e = a.s[seg].off[node + 1];
    f32x4 acc0 = {0.f, 0.f, 0.f, 0.f}, acc1 = {0.f, 0.f, 0.f, 0.f};
    int i = s;
    for (; i + 2 <= e; i += 2) {
        int r0 = rows[i], r1 = rows[i + 1];
        bf16x4 x = *(const bf16x4*)&hsrc[(size_t)r0 * HID + sub * 4];
        bf16x4 y = *(const bf16x4*)&hsrc[(size_t)r1 * HID + sub * 4];
        acc0[0] += (float)x[0]; acc0[1] += (float)x[1]; acc0[2] += (float)x[2]; acc0[3] += (float)x[3];
        acc1[0] += (float)y[0]; acc1[1] += (float)y[1]; acc1[2] += (float)y[2]; acc1[3] += (float)y[3];
    }
    if (i < e) {
        bf16x4 x = *(const bf16x4*)&hsrc[(size_t)rows[i] * HID + sub * 4];
        acc0[0] += (float)x[0]; acc0[1] += (float)x[1]; acc0[2] += (float)x[2]; acc0[3] += (float)x[3];
    }
    f32x4 acc = acc0 + acc1;
    float inv = (e > s) ? 1.0f / (float)(e - s) : 0.0f;
    bf16x4 o;
    o[0] = (__bf16)(acc[0] * inv); o[1] = (__bf16)(acc[1] * inv);
    o[2] = (__bf16)(acc[2] * inv); o[3] = (__bf16)(acc[3] * inv);
    *(bf16x4*)&a.s[seg].out[(size_t)node * a.s[seg].ldo + sub * 4] = o;
}

// base = fp16(0.1*H + genes: 0.9*dinv*sum_{v->g} h_v); z0 = fp16(H)
__global__ void base_kernel(const float* __restrict__ H, const int* __restrict__ r0rows,
                            const int* __restrict__ r0off, const float* __restrict__ dinv,
                            _Float16* __restrict__ base, _Float16* __restrict__ z0)
{
    int t = threadIdx.x;
    int node = blockIdx.x * 8 + (t >> 5);
    int sub = t & 31;
    size_t idx = (size_t)node * HID + sub * 4;
    f32x4 h = *(const f32x4*)&H[idx];
    f32x4 acc = {0.f, 0.f, 0.f, 0.f};
    if (node < N_GENE) {
        for (int i = r0off[node]; i < r0off[node + 1]; i++) {
            acc += *(const f32x4*)&H[(size_t)(OV + r0rows[i]) * HID + sub * 4];
        }
        acc *= 0.9f * dinv[node];
    }
    f32x4 b = h * 0.1f + acc;
    f16x4 bo, z;
    bo[0] = (_Float16)b[0]; bo[1] = (_Float16)b[1]; bo[2] = (_Float16)b[2]; bo[3] = (_Float16)b[3];
    z[0] = (_Float16)h[0]; z[1] = (_Float16)h[1]; z[2] = (_Float16)h[2]; z[3] = (_Float16)h[3];
    *(f16x4*)&base[idx] = bo;
    *(f16x4*)&z0[idx] = z;
}

template<typename OT>
__launch_bounds__(256)
__global__ void appnp_kernel(const _Float16* __restrict__ zin, OT* __restrict__ zout,
                             const _Float16* __restrict__ base,
                             const int* __restrict__ rows, const float* __restrict__ wts,
                             const int* __restrict__ off, const float* __restrict__ dinv)
{
    int t = threadIdx.x;
    int c = blockIdx.x * 8 + (t >> 5);
    int sub = t & 31;
    int s = off[c], e = off[c + 1];
    f32x4 acc0 = {0.f, 0.f, 0.f, 0.f}, acc1 = {0.f, 0.f, 0.f, 0.f};
    int i = s;
    for (; i + 2 <= e; i += 2) {
        int r0 = rows[i], r1 = rows[i + 1];
        float w0 = wts[i], w1 = wts[i + 1];
        f16x4 x = *(const f16x4*)&zin[(size_t)r0 * HID + sub * 4];
        f16x4 y = *(const f16x4*)&zin[(size_t)r1 * HID + sub * 4];
        acc0[0] += (float)x[0] * w0; acc0[1] += (float)x[1] * w0;
        acc0[2] += (float)x[2] * w0; acc0[3] += (float)x[3] * w0;
        acc1[0] += (float)y[0] * w1; acc1[1] += (float)y[1] * w1;
        acc1[2] += (float)y[2] * w1; acc1[3] += (float)y[3] * w1;
    }
    if (i < e) {
        float w0 = wts[i];
        f16x4 x = *(const f16x4*)&zin[(size_t)rows[i] * HID + sub * 4];
        acc0[0] += (float)x[0] * w0; acc0[1] += (float)x[1] * w0;
        acc0[2] += (float)x[2] * w0; acc0[3] += (float)x[3] * w0;
    }
    f32x4 acc = acc0 + acc1;
    float dc = dinv[c];
    size_t idx = (size_t)c * HID + sub * 4;
    f16x4 zi = *(const f16x4*)&zin[idx];
    f16x4 bs = *(const f16x4*)&base[idx];
    f32x4 res;
    float d2 = dc * dc;
#pragma unroll
    for (int j = 0; j < 4; j++) res[j] = 0.9f * (dc * acc[j] + d2 * (float)zi[j]) + (float)bs[j];
    if constexpr (sizeof(OT) == 2) {
        f16x4 o;
        o[0] = (_Float16)res[0]; o[1] = (_Float16)res[1]; o[2] = (_Float16)res[2]; o[3] = (_Float16)res[3];
        *(f16x4*)&zout[idx] = o;
    } else {
        *(f32x4*)&zout[idx] = res;
    }
}

// ---------------- weight prep ----------------

// one launch: convert win_g/win_p/win_v to bf16
__global__ void cvt3_kernel(const float* __restrict__ g, const float* __restrict__ p,
                            const float* __restrict__ v, __bf16* __restrict__ og,
                            __bf16* __restrict__ op, __bf16* __restrict__ ov)
{
    int i = blockIdx.x * 256 + threadIdx.x;
    if (i < 32768) og[i] = (__bf16)g[i];
    if (i < 16384) op[i] = (__bf16)p[i];
    if (i < 8192)  ov[i] = (__bf16)v[i];
}

// Wg: [128][512] = [WL0|WL2|WL3|WR0+WR2+WR3]; Wp: [128][256] = [WL1|WR1]; both layers (blockIdx.y)
__global__ void prep_sage_kernel(const float* __restrict__ wsl, const float* __restrict__ bsl,
                                 const float* __restrict__ wsr,
                                 __bf16* __restrict__ Wg0, __bf16* __restrict__ Wg1,
                                 __bf16* __restrict__ Wp0, __bf16* __restrict__ Wp1,
                                 float* __restrict__ bg0, float* __restrict__ bg1,
                                 float* __restrict__ bp0, float* __restrict__ bp1)
{
    int layer = blockIdx.y;
    int i = blockIdx.x * 256 + threadIdx.x;
    const float* WL = wsl + (size_t)layer * 4 * HID * HID;
    const float* WR = wsr + (size_t)layer * 4 * HID * HID;
    __bf16* Wg = layer ? Wg1 : Wg0;
    __bf16* Wp = layer ? Wp1 : Wp0;
    float* bg = layer ? bg1 : bg0;
    float* bp = layer ? bp1 : bp0;
    if (i < 128 * 512) {
        int nr = i >> 9, k = i & 511;
        float v;
        if (k < 128)      v = WL[0 * 16384 + nr * 128 + k];
        else if (k < 256) v = WL[2 * 16384 + nr * 128 + (k - 128)];
        else if (k < 384) v = WL[3 * 16384 + nr * 128 + (k - 256)];
        else {
            int kk = k - 384;
            v = WR[0 * 16384 + nr * 128 + kk] + WR[2 * 16384 + nr * 128 + kk] + WR[3 * 16384 + nr * 128 + kk];
        }
        Wg[i] = (__bf16)v;
    }
    if (i < 128 * 256) {
        int nr = i >> 8, k = i & 255;
        float v = (k < 128) ? WL[1 * 16384 + nr * 128 + k] : WR[1 * 16384 + nr * 128 + (k - 128)];
        Wp[i] = (__bf16)v;
    }
    if (i < 128) {
        const float* BL = bsl + (size_t)layer * 4 * HID;
        bg[i] = BL[0 * 128 + i] + BL[2 * 128 + i] + BL[3 * 128 + i];
        bp[i] = BL[1 * 128 + i];
    }
}

// ---------------- tiled MFMA GEMM with LDS-staged W ----------------
// OUT[M,128]: block = 128 rows (4 waves x 32 rows), K chunked by 32, W chunk (8 KB) in LDS.
// verified layouts: A[m=lane&15][k=quad*8+j]; B: n=lane&15, same k slice; C/D: col=lane&15, row=quad*4+reg.
// LDS row stride 40 elements (80 B): r and r+8 alias the same banks -> free 2-way.
// A_F32=true: A1 = float[M][KT] (projection).  SAGE=true: A1 = bf16[M][KT-128], A2 = Hbf[M][128];
// epilogue does H = relu(H + scale*(gemm+bias)) in-place (each wave touches only its own rows).

template<int KT, bool A_F32, bool SAGE>
__launch_bounds__(256)
__global__ void tgemm_kernel(const void* __restrict__ A1_, const __bf16* __restrict__ A2,
                             const __bf16* __restrict__ W, const float* __restrict__ bias,
                             float scale, float* __restrict__ H, __bf16* __restrict__ Hbf, int M)
{
    constexpr int K1 = SAGE ? (KT - 128) : KT;
    __shared__ __bf16 lds[128 * 40];
    int t = threadIdx.x;
    int wave = t >> 6, lane = t & 63;
    int r = lane & 15, quad = lane >> 4;
    int mbase = blockIdx.x * 128 + wave * 32;
    int mm0 = min(mbase + r, M - 1);
    int mm1 = min(mbase + 16 + r, M - 1);
    const float* Af = (const float*)A1_;
    const __bf16* Ab = (const __bf16*)A1_;

    f32x4 acc[2][8];
#pragma unroll
    for (int s = 0; s < 2; s++)
#pragma unroll
        for (int n = 0; n < 8; n++) acc[s][n] = (f32x4){0.f, 0.f, 0.f, 0.f};

    int srow = t >> 1;            // staging: 2 rows/thread-pair
    int selt = (t & 1) * 16;      // element offset within row chunk (16 elements = 32 B)

    for (int k0 = 0; k0 < KT; k0 += 32) {
        __syncthreads();
        {
            const __bf16* wsrc = W + (size_t)srow * KT + k0 + selt;
            bf16x8 w0 = *(const bf16x8*)wsrc;
            bf16x8 w1 = *(const bf16x8*)(wsrc + 8);
            *(bf16x8*)&lds[srow * 40 + selt] = w0;
            *(bf16x8*)&lds[srow * 40 + selt + 8] = w1;
        }
        bf16x8 a0, a1;
        if constexpr (A_F32) {
            const float* p0 = Af + (size_t)mm0 * KT + k0 + quad * 8;
            const float* p1 = Af + (size_t)mm1 * KT + k0 + quad * 8;
            f32x4 x0 = *(const f32x4*)p0, x1 = *(const f32x4*)(p0 + 4);
            f32x4 y0 = *(const f32x4*)p1, y1 = *(const f32x4*)(p1 + 4);
#pragma unroll
            for (int j = 0; j < 4; j++) { a0[j] = (__bf16)x0[j]; a0[j + 4] = (__bf16)x1[j]; }
#pragma unroll
            for (int j = 0; j < 4; j++) { a1[j] = (__bf16)y0[j]; a1[j + 4] = (__bf16)y1[j]; }
        } else {
            if (k0 < K1) {
                a0 = *(const bf16x8*)(Ab + (size_t)mm0 * K1 + k0 + quad * 8);
                a1 = *(const bf16x8*)(Ab + (size_t)mm1 * K1 + k0 + quad * 8);
            } else {
                a0 = *(const bf16x8*)(A2 + (size_t)mm0 * 128 + (k0 - K1) + quad * 8);
                a1 = *(const bf16x8*)(A2 + (size_t)mm1 * 128 + (k0 - K1) + quad * 8);
            }
        }
        __syncthreads();
#pragma unroll
        for (int nt = 0; nt < 8; nt++) {
            bf16x8 b = *(const bf16x8*)&lds[(nt * 16 + r) * 40 + quad * 8];
            acc[0][nt] = __builtin_amdgcn_mfma_f32_16x16x32_bf16(a0, b, acc[0][nt], 0, 0, 0);
            acc[1][nt] = __builtin_amdgcn_mfma_f32_16x16x32_bf16(a1, b, acc[1][nt], 0, 0, 0);
        }
    }

#pragma unroll
    for (int sub = 0; sub < 2; sub++) {
#pragma unroll
        for (int nt = 0; nt < 8; nt++) {
            int n = nt * 16 + r;
            float bv = bias[n];
#pragma unroll
            for (int i = 0; i < 4; i++) {
                int row = mbase + sub * 16 + quad * 4 + i;
                if (row >= M) continue;
                size_t idx = (size_t)row * HID + n;
                float v;
                if constexpr (SAGE) v = fmaxf(H[idx] + (acc[sub][nt][i] + bv) * scale, 0.f);
                else                v = fmaxf(acc[sub][nt][i] + bv, 0.f);
                H[idx] = v;
                Hbf[idx] = (__bf16)v;
            }
        }
    }
}

// ---------------- driver ----------------

extern "C" void kernel_launch(void* const* d_in, const int* in_sizes, int n_in,
                              void* d_out, int out_size, void* d_ws, size_t ws_size,
                              hipStream_t stream)
{
    (void)in_sizes; (void)n_in; (void)out_size; (void)ws_size;

    const float* x_gene = (const float*)d_in[0];
    const float* x_path = (const float*)d_in[1];
    const float* x_vacc = (const float*)d_in[2];
    const float* win_g  = (const float*)d_in[3];
    const float* bin_g  = (const float*)d_in[4];
    const float* win_p  = (const float*)d_in[5];
    const float* bin_p  = (const float*)d_in[6];
    const float* win_v  = (const float*)d_in[7];
    const float* bin_v  = (const float*)d_in[8];
    const float* wsl    = (const float*)d_in[9];
    const float* bsl    = (const float*)d_in[10];
    const float* wsr    = (const float*)d_in[11];
    const int* ei_tg  = (const int*)d_in[12];
    const int* ei_ing = (const int*)d_in[13];
    const int* ei_ct  = (const int*)d_in[14];
    const int* ei_ii  = (const int*)d_in[15];

    char* p = (char*)d_ws;
    auto alloc = [&](size_t b) { char* r = p; p += (b + 255) & ~((size_t)255); return r; };

    float*    H    = (float*)alloc((size_t)N_TOT * HID * 4);
    _Float16* BASE = (_Float16*)alloc((size_t)N_TOT * HID * 2);
    __bf16*   Hbf  = (__bf16*)alloc((size_t)N_TOT * HID * 2);
    _Float16* Z1   = (_Float16*)alloc((size_t)N_TOT * HID * 2);
    _Float16* Z2   = (_Float16*)alloc((size_t)N_TOT * HID * 2);
    __bf16* AGG_G = (__bf16*)alloc((size_t)N_GENE * 384 * 2);
    __bf16* AGG_P = (__bf16*)alloc((size_t)N_PATH * 128 * 2);
    int*   a_rows = (int*)alloc((size_t)3 * E_PER * 4);
    float* a_wts  = (float*)alloc((size_t)3 * E_PER * 4);
    int*   a_off  = (int*)alloc((size_t)(N_TOT + 1) * 4);
    float* dinv   = (float*)alloc((size_t)N_TOT * 4);
    int* r_rows[4], *r_off[4];
    for (int r = 0; r < 4; r++) r_rows[r] = (int*)alloc((size_t)E_PER * 4);
    r_off[0] = (int*)alloc((size_t)(N_GENE + 1) * 4);
    r_off[1] = (int*)alloc((size_t)(N_PATH + 1) * 4);
    r_off[2] = (int*)alloc((size_t)(N_GENE + 1) * 4);
    r_off[3] = (int*)alloc((size_t)(N_GENE + 1) * 4);
    int* partials = (int*)alloc((size_t)5 * 32 * 4);
    __bf16* wbf_g = (__bf16*)alloc((size_t)HID * 256 * 2);
    __bf16* wbf_p = (__bf16*)alloc((size_t)HID * 128 * 2);
    __bf16* wbf_v = (__bf16*)alloc((size_t)HID * 64 * 2);
    __bf16* Wg[2]; __bf16* Wp[2]; float* bg[2]; float* bp[2];
    for (int l = 0; l < 2; l++) {
        Wg[l] = (__bf16*)alloc((size_t)128 * 512 * 2);
        Wp[l] = (__bf16*)alloc((size_t)128 * 256 * 2);
        bg[l] = (float*)alloc(128 * 4);
        bp[l] = (float*)alloc(128 * 4);
    }
    char* zb = p;
    int* cnt = (int*)alloc((size_t)CNT_TOTAL * 4);
    int* cur = (int*)alloc((size_t)CNT_TOTAL * 4);
    hipMemsetAsync(zb, 0, (size_t)(p - zb), stream);

    Off5 offs;
    offs.p[0] = a_off; offs.p[1] = r_off[0]; offs.p[2] = r_off[1];
    offs.p[3] = r_off[2]; offs.p[4] = r_off[3];

    const int GE = (E_PER + 255) / 256;
    const int TB_G = (N_GENE + 127) / 128;   // 391
    const int TB_P = (N_PATH + 127) / 128;   // 157
    const int TB_V = (N_VACC + 127) / 128;   // 79

    // --- weight prep ---
    cvt3_kernel<<<128, 256, 0, stream>>>(win_g, win_p, win_v, wbf_g, wbf_p, wbf_v);
    prep_sage_kernel<<<dim3(256, 2), 256, 0, stream>>>(wsl, bsl, wsr, Wg[0], Wg[1], Wp[0], Wp[1],
                                                       bg[0], bg[1], bp[0], bp[1]);

    // --- CSR counts ---
    Cnt7 c7;
    c7.s[0] = {ei_ing + E_PER, cnt + OP};
    c7.s[1] = {ei_ct + E_PER,  cnt + OG};
    c7.s[2] = {ei_ii + E_PER,  cnt + OG};
    c7.s[3] = {ei_tg + E_PER,  cnt + 80000};
    c7.s[4] = {ei_ing + E_PER, cnt + 130000};
    c7.s[5] = {ei_ct + E_PER,  cnt + 150000};
    c7.s[6] = {ei_ii + E_PER,  cnt + 200000};
    count_all_kernel<<<dim3(GE, 7), 256, 0, stream>>>(c7);

    dim3 sg((N_TOT + 4095) / 4096, 5);
    scan1_kernel<<<sg, 256, 0, stream>>>(cnt, partials);
    scan2_kernel<<<1, 64, 0, stream>>>(partials, offs);
    scan3_kernel<<<sg, 256, 0, stream>>>(cnt, partials, offs);

    dinv_kernel<<<(N_TOT + 255) / 256, 256, 0, stream>>>(a_off, r_off[0], dinv);

    FillA3 fa;
    fa.s[0] = {ei_ing, OG, OP};
    fa.s[1] = {ei_ct,  OP, OG};
    fa.s[2] = {ei_ii,  OG, OG};
    fill_appnp_kernel<<<dim3(GE, 3), 256, 0, stream>>>(fa, a_off, cur, a_rows, a_wts, dinv);
    FillR4 fr;
    fr.s[0] = {ei_tg,  r_off[0], cur + 80000,  r_rows[0]};
    fr.s[1] = {ei_ing, r_off[1], cur + 130000, r_rows[1]};
    fr.s[2] = {ei_ct,  r_off[2], cur + 150000, r_rows[2]};
    fr.s[3] = {ei_ii,  r_off[3], cur + 200000, r_rows[3]};
    fill_rel_kernel<<<dim3(GE, 4), 256, 0, stream>>>(fr);

    // --- input projections ---
    tgemm_kernel<256, true, false><<<TB_G, 256, 0, stream>>>(x_gene, nullptr, wbf_g, bin_g, 1.f, H, Hbf, N_GENE);
    tgemm_kernel<128, true, false><<<TB_P, 256, 0, stream>>>(x_path, nullptr, wbf_p, bin_p, 1.f,
                                                             H + (size_t)OP * HID, Hbf + (size_t)OP * HID, N_PATH);
    tgemm_kernel< 64, true, false><<<TB_V, 256, 0, stream>>>(x_vacc, nullptr, wbf_v, bin_v, 1.f,
                                                             H + (size_t)OV * HID, Hbf + (size_t)OV * HID, N_VACC);

    // --- 2 hetero-SAGE layers ---
    for (int l = 0; l < 2; l++) {
        Agg4 ag;
        ag.s[0] = {Hbf + (size_t)OV * HID, r_rows[0], r_off[0], AGG_G + 0,   384, N_GENE};
        ag.s[1] = {Hbf + (size_t)OP * HID, r_rows[2], r_off[2], AGG_G + 128, 384, N_GENE};
        ag.s[2] = {Hbf,                    r_rows[3], r_off[3], AGG_G + 256, 384, N_GENE};
        ag.s[3] = {Hbf,                    r_rows[1], r_off[1], AGG_P,       128, N_PATH};
        agg_all_kernel<<<dim3(N_GENE / 8, 4), 256, 0, stream>>>(ag);
        tgemm_kernel<512, false, true><<<TB_G, 256, 0, stream>>>(AGG_G, Hbf, Wg[l], bg[l], 1.0f / 3.0f,
                                                                 H, Hbf, N_GENE);
        tgemm_kernel<256, false, true><<<TB_P, 256, 0, stream>>>(AGG_P, Hbf + (size_t)OP * HID, Wp[l], bp[l], 1.0f,
                                                                 H + (size_t)OP * HID, Hbf + (size_t)OP * HID, N_PATH);
    }

    // --- APPNP ---
    base_kernel<<<N_TOT / 8, 256, 0, stream>>>(H, r_rows[0], r_off[0], dinv, BASE, Z1);

    float* dout = (float*)d_out;
    appnp_kernel<<<N_TOT / 8, 256, 0, stream>>>(Z1, Z2, BASE, a_rows, a_wts, a_off, dinv);
    appnp_kernel<<<N_TOT / 8, 256, 0, stream>>>(Z2, Z1, BASE, a_rows, a_wts, a_off, dinv);
    appnp_kernel<<<N_TOT / 8, 256, 0, stream>>>(Z1, Z2, BASE, a_rows, a_wts, a_off, dinv);
    appnp_kernel<<<N_TOT / 8, 256, 0, stream>>>(Z2, Z1, BASE, a_rows, a_wts, a_off, dinv);
    appnp_kernel<<<N_TOT / 8, 256, 0, stream>>>(Z1, Z2, BASE, a_rows, a_wts, a_off, dinv);
    appnp_kernel<<<N_TOT / 8, 256, 0, stream>>>(Z2, Z1, BASE, a_rows, a_wts, a_off, dinv);
    appnp_kernel<<<N_TOT / 8, 256, 0, stream>>>(Z1, Z2, BASE, a_rows, a_wts, a_off, dinv);
    appnp_kernel<<<N_TOT / 8, 256, 0, stream>>>(Z2, dout, BASE, a_rows, a_wts, a_off, dinv);
}

// Round 6
// 848.799 us; speedup vs baseline: 2.8499x; 1.1067x over previous
//
#include <hip/hip_runtime.h>

#define N_GENE 50000
#define N_PATH 20000
#define N_VACC 10000
#define N_TOT  80000
#define HID    128
#define E_PER  250000
#define OG 0
#define OP 50000
#define OV 70000

typedef __bf16    bf16x8 __attribute__((ext_vector_type(8)));
typedef __bf16    bf16x4 __attribute__((ext_vector_type(4)));
typedef _Float16  f16x4  __attribute__((ext_vector_type(4)));
typedef float     f32x4  __attribute__((ext_vector_type(4)));

// count buffer: 4 relation segments (dst-local)
// seg0: rel0 targets (dst gene) | seg1: rel1 in (dst pathway) | seg2: rel2 contains (dst gene) | seg3: rel3 interacts (dst gene)
__constant__ int c_segn[4] = {N_GENE, N_PATH, N_GENE, N_GENE};
__constant__ int c_segb[4] = {0, 50000, 70000, 120000};
#define CNT_TOTAL 170000

struct Off4 { int* p[4]; };
struct CntSeg { const int* dst; int* cnt; };
struct Cnt4 { CntSeg s[4]; };
struct F4Seg { const int* ei; const int* off; int* rows; int soff; };
struct F4 { F4Seg s[4]; };
struct W3Seg { const int* rows; float* w; };
struct W3 { W3Seg s[3]; };
struct AggSeg { const int* rows; const int* off; __bf16* out; int ldo; int n; };
struct Agg4 { AggSeg s[4]; };
struct Csr { const int* off; const int* rows; const float* w; };

// ---------------- CSR build ----------------

__global__ void count4_kernel(Cnt4 a, int* __restrict__ rank)
{
    int seg = blockIdx.y;
    int e = blockIdx.x * 256 + threadIdx.x;
    if (e < E_PER) rank[seg * E_PER + e] = atomicAdd(&a.s[seg].cnt[a.s[seg].dst[e]], 1);
}

__global__ void scan1_kernel(const int* __restrict__ cnt, int* __restrict__ partials)
{
    int seg = blockIdx.y, blk = blockIdx.x;
    int n = c_segn[seg];
    if (blk >= ((n + 4095) >> 12)) return;
    const int* base = cnt + c_segb[seg];
    int t = threadIdx.x;
    int i0 = (blk << 12) + t * 16;
    int s = 0;
#pragma unroll
    for (int j = 0; j < 16; j++) { int i = i0 + j; if (i < n) s += base[i]; }
    __shared__ int sh[256];
    sh[t] = s; __syncthreads();
    for (int d = 128; d; d >>= 1) { if (t < d) sh[t] += sh[t + d]; __syncthreads(); }
    if (t == 0) partials[seg * 32 + blk] = sh[0];
}

__global__ void scan2_kernel(int* __restrict__ partials, Off4 offs)
{
    int s = threadIdx.x;
    if (s < 4) {
        int n = c_segn[s];
        int nb = (n + 4095) >> 12;
        int run = 0;
        for (int b = 0; b < nb; b++) { int v = partials[s * 32 + b]; partials[s * 32 + b] = run; run += v; }
        offs.p[s][n] = run;
    }
}

__global__ void scan3_kernel(const int* __restrict__ cnt, const int* __restrict__ partials, Off4 offs)
{
    int seg = blockIdx.y, blk = blockIdx.x;
    int n = c_segn[seg];
    if (blk >= ((n + 4095) >> 12)) return;
    const int* base = cnt + c_segb[seg];
    int* off = offs.p[seg];
    int t = threadIdx.x;
    int i0 = (blk << 12) + t * 16;
    int loc[16];
    int s = 0;
#pragma unroll
    for (int j = 0; j < 16; j++) { int i = i0 + j; int v = (i < n) ? base[i] : 0; loc[j] = s; s += v; }
    __shared__ int sh[256];
    sh[t] = s; __syncthreads();
    for (int d = 1; d < 256; d <<= 1) {
        int v = (t >= d) ? sh[t - d] : 0; __syncthreads();
        sh[t] += v; __syncthreads();
    }
    int base_off = sh[t] - s + partials[seg * 32 + blk];
#pragma unroll
    for (int j = 0; j < 16; j++) { int i = i0 + j; if (i < n) off[i] = base_off + loc[j]; }
}

// degrees from relation offsets; vaccine deg = 1 (self loop)
__global__ void dinv_kernel(const int* __restrict__ r0, const int* __restrict__ r1,
                            const int* __restrict__ r2, const int* __restrict__ r3,
                            float* __restrict__ dinv)
{
    int i = blockIdx.x * 256 + threadIdx.x;
    if (i >= N_TOT) return;
    int deg = 1;
    if (i < N_GENE) deg += (r0[i + 1] - r0[i]) + (r2[i + 1] - r2[i]) + (r3[i + 1] - r3[i]);
    else if (i < OV) { int k = i - OP; deg += r1[k + 1] - r1[k]; }
    dinv[i] = rsqrtf((float)deg);
}

// non-atomic fill using ranks captured during count; stores GLOBAL src ids
__global__ void fill4_kernel(F4 a, const int* __restrict__ rank)
{
    int seg = blockIdx.y;
    int e = blockIdx.x * 256 + threadIdx.x;
    if (e >= E_PER) return;
    const int* ei = a.s[seg].ei;
    int s = ei[e] + a.s[seg].soff;
    int d = ei[E_PER + e];
    int pos = a.s[seg].off[d] + rank[seg * E_PER + e];
    a.s[seg].rows[pos] = s;
}

// per-edge weights aligned to rel CSRs: w[j] = dinv[rows[j]]
__global__ void wts3_kernel(W3 a, const float* __restrict__ dinv)
{
    int seg = blockIdx.y;
    int e = blockIdx.x * 256 + threadIdx.x;
    if (e < E_PER) a.s[seg].w[e] = dinv[a.s[seg].rows[e]];
}

// ---------------- gather kernels ----------------

__global__ void agg_all_kernel(Agg4 a, const __bf16* __restrict__ Hbf)
{
    int seg = blockIdx.y;
    int t = threadIdx.x;
    int node = blockIdx.x * 8 + (t >> 5);
    if (node >= a.s[seg].n) return;
    const int* rows = a.s[seg].rows;
    int sub = t & 31;
    int s = a.s[seg].off[node], e = a.s[seg].off[node + 1];
    f32x4 acc0 = {0.f, 0.f, 0.f, 0.f}, acc1 = {0.f, 0.f, 0.f, 0.f};
    int i = s;
    for (; i + 2 <= e; i += 2) {
        int r0 = rows[i], r1 = rows[i + 1];
        bf16x4 x = *(const bf16x4*)&Hbf[(size_t)r0 * HID + sub * 4];
        bf16x4 y = *(const bf16x4*)&Hbf[(size_t)r1 * HID + sub * 4];
        acc0[0] += (float)x[0]; acc0[1] += (float)x[1]; acc0[2] += (float)x[2]; acc0[3] += (float)x[3];
        acc1[0] += (float)y[0]; acc1[1] += (float)y[1]; acc1[2] += (float)y[2]; acc1[3] += (float)y[3];
    }
    if (i < e) {
        bf16x4 x = *(const bf16x4*)&Hbf[(size_t)rows[i] * HID + sub * 4];
        acc0[0] += (float)x[0]; acc0[1] += (float)x[1]; acc0[2] += (float)x[2]; acc0[3] += (float)x[3];
    }
    f32x4 acc = acc0 + acc1;
    float inv = (e > s) ? 1.0f / (float)(e - s) : 0.0f;
    bf16x4 o;
    o[0] = (__bf16)(acc[0] * inv); o[1] = (__bf16)(acc[1] * inv);
    o[2] = (__bf16)(acc[2] * inv); o[3] = (__bf16)(acc[3] * inv);
    *(bf16x4*)&a.s[seg].out[(size_t)node * a.s[seg].ldo + sub * 4] = o;
}

// base = fp16(0.1*H + genes: 0.9*dinv*sum_{v->g} h_v); z0 = fp16(H); vaccine rows -> dout (fixpoint)
__global__ void base_kernel(const float* __restrict__ H, const int* __restrict__ r0rows,
                            const int* __restrict__ r0off, const float* __restrict__ dinv,
                            _Float16* __restrict__ base, _Float16* __restrict__ z0,
                            float* __restrict__ dout)
{
    int t = threadIdx.x;
    int node = blockIdx.x * 8 + (t >> 5);
    int sub = t & 31;
    size_t idx = (size_t)node * HID + sub * 4;
    f32x4 h = *(const f32x4*)&H[idx];
    if (node >= OV) { *(f32x4*)&dout[idx] = h; return; }
    f32x4 acc = {0.f, 0.f, 0.f, 0.f};
    if (node < N_GENE) {
        for (int i = r0off[node]; i < r0off[node + 1]; i++) {
            acc += *(const f32x4*)&H[(size_t)r0rows[i] * HID + sub * 4];  // global vaccine ids
        }
        acc *= 0.9f * dinv[node];
    }
    f32x4 b = h * 0.1f + acc;
    f16x4 bo, z;
    bo[0] = (_Float16)b[0]; bo[1] = (_Float16)b[1]; bo[2] = (_Float16)b[2]; bo[3] = (_Float16)b[3];
    z[0] = (_Float16)h[0]; z[1] = (_Float16)h[1]; z[2] = (_Float16)h[2]; z[3] = (_Float16)h[3];
    *(f16x4*)&base[idx] = bo;
    *(f16x4*)&z0[idx] = z;
}

__device__ __forceinline__ void gath(const int* __restrict__ off, const int* __restrict__ rows,
                                     const float* __restrict__ w, int node, int sub,
                                     const _Float16* __restrict__ zin, f32x4& a0, f32x4& a1)
{
    int s = off[node], e = off[node + 1];
    int i = s;
    for (; i + 2 <= e; i += 2) {
        int r0 = rows[i], r1 = rows[i + 1];
        float w0 = w[i], w1 = w[i + 1];
        f16x4 x = *(const f16x4*)&zin[(size_t)r0 * HID + sub * 4];
        f16x4 y = *(const f16x4*)&zin[(size_t)r1 * HID + sub * 4];
        a0[0] += (float)x[0] * w0; a0[1] += (float)x[1] * w0;
        a0[2] += (float)x[2] * w0; a0[3] += (float)x[3] * w0;
        a1[0] += (float)y[0] * w1; a1[1] += (float)y[1] * w1;
        a1[2] += (float)y[2] * w1; a1[3] += (float)y[3] * w1;
    }
    if (i < e) {
        float w0 = w[i];
        f16x4 x = *(const f16x4*)&zin[(size_t)rows[i] * HID + sub * 4];
        a0[0] += (float)x[0] * w0; a0[1] += (float)x[1] * w0;
        a0[2] += (float)x[2] * w0; a0[3] += (float)x[3] * w0;
    }
}

// covers columns [0, 70000) only; vaccine columns are fixpoints handled in base_kernel
template<typename OT>
__launch_bounds__(256)
__global__ void appnp_kernel(const _Float16* __restrict__ zin, OT* __restrict__ zout,
                             const _Float16* __restrict__ base,
                             Csr c1, Csr c2, Csr c3, const float* __restrict__ dinv)
{
    int t = threadIdx.x;
    int c = blockIdx.x * 8 + (t >> 5);
    int sub = t & 31;
    f32x4 a0 = {0.f, 0.f, 0.f, 0.f}, a1 = {0.f, 0.f, 0.f, 0.f};
    if (c < OP) {
        gath(c2.off, c2.rows, c2.w, c, sub, zin, a0, a1);
        gath(c3.off, c3.rows, c3.w, c, sub, zin, a0, a1);
    } else {
        gath(c1.off, c1.rows, c1.w, c - OP, sub, zin, a0, a1);
    }
    f32x4 acc = a0 + a1;
    float dc = dinv[c];
    size_t idx = (size_t)c * HID + sub * 4;
    f16x4 zi = *(const f16x4*)&zin[idx];
    f16x4 bs = *(const f16x4*)&base[idx];
    f32x4 res;
    float d2 = dc * dc;
#pragma unroll
    for (int j = 0; j < 4; j++) res[j] = 0.9f * (dc * acc[j] + d2 * (float)zi[j]) + (float)bs[j];
    if constexpr (sizeof(OT) == 2) {
        f16x4 o;
        o[0] = (_Float16)res[0]; o[1] = (_Float16)res[1]; o[2] = (_Float16)res[2]; o[3] = (_Float16)res[3];
        *(f16x4*)&zout[idx] = o;
    } else {
        *(f32x4*)&zout[idx] = res;
    }
}

// ---------------- weight prep (one launch: y=0 cvt inputs, y=1/2 sage layers) ----------------

__global__ void prep_all_kernel(const float* __restrict__ wg, const float* __restrict__ wp,
                                const float* __restrict__ wv,
                                __bf16* __restrict__ obg, __bf16* __restrict__ obp, __bf16* __restrict__ obv,
                                const float* __restrict__ wsl, const float* __restrict__ bsl,
                                const float* __restrict__ wsr,
                                __bf16* __restrict__ Wg0, __bf16* __restrict__ Wg1,
                                __bf16* __restrict__ Wp0, __bf16* __restrict__ Wp1,
                                float* __restrict__ bg0, float* __restrict__ bg1,
                                float* __restrict__ bp0, float* __restrict__ bp1)
{
    int y = blockIdx.y;
    int i = blockIdx.x * 256 + threadIdx.x;
    if (y == 0) {
        if (i < 32768) obg[i] = (__bf16)wg[i];
        if (i < 16384) obp[i] = (__bf16)wp[i];
        if (i < 8192)  obv[i] = (__bf16)wv[i];
        return;
    }
    int layer = y - 1;
    const float* WL = wsl + (size_t)layer * 4 * HID * HID;
    const float* WR = wsr + (size_t)layer * 4 * HID * HID;
    __bf16* Wg = layer ? Wg1 : Wg0;
    __bf16* Wp = layer ? Wp1 : Wp0;
    float* bg = layer ? bg1 : bg0;
    float* bp = layer ? bp1 : bp0;
    if (i < 128 * 512) {
        int nr = i >> 9, k = i & 511;
        float v;
        if (k < 128)      v = WL[0 * 16384 + nr * 128 + k];
        else if (k < 256) v = WL[2 * 16384 + nr * 128 + (k - 128)];
        else if (k < 384) v = WL[3 * 16384 + nr * 128 + (k - 256)];
        else {
            int kk = k - 384;
            v = WR[0 * 16384 + nr * 128 + kk] + WR[2 * 16384 + nr * 128 + kk] + WR[3 * 16384 + nr * 128 + kk];
        }
        Wg[i] = (__bf16)v;
    }
    if (i < 128 * 256) {
        int nr = i >> 8, k = i & 255;
        float v = (k < 128) ? WL[1 * 16384 + nr * 128 + k] : WR[1 * 16384 + nr * 128 + (k - 128)];
        Wp[i] = (__bf16)v;
    }
    if (i < 128) {
        const float* BL = bsl + (size_t)layer * 4 * HID;
        bg[i] = BL[0 * 128 + i] + BL[2 * 128 + i] + BL[3 * 128 + i];
        bp[i] = BL[1 * 128 + i];
    }
}

// ---------------- tiled MFMA GEMM with LDS-staged W (verified r5) ----------------

template<int KT, bool A_F32, bool SAGE>
__launch_bounds__(256)
__global__ void tgemm_kernel(const void* __restrict__ A1_, const __bf16* __restrict__ A2,
                             const __bf16* __restrict__ W, const float* __restrict__ bias,
                             float scale, float* __restrict__ H, __bf16* __restrict__ Hbf, int M)
{
    constexpr int K1 = SAGE ? (KT - 128) : KT;
    __shared__ __bf16 lds[128 * 40];
    int t = threadIdx.x;
    int wave = t >> 6, lane = t & 63;
    int r = lane & 15, quad = lane >> 4;
    int mbase = blockIdx.x * 128 + wave * 32;
    int mm0 = min(mbase + r, M - 1);
    int mm1 = min(mbase + 16 + r, M - 1);
    const float* Af = (const float*)A1_;
    const __bf16* Ab = (const __bf16*)A1_;

    f32x4 acc[2][8];
#pragma unroll
    for (int s = 0; s < 2; s++)
#pragma unroll
        for (int n = 0; n < 8; n++) acc[s][n] = (f32x4){0.f, 0.f, 0.f, 0.f};

    int srow = t >> 1;
    int selt = (t & 1) * 16;

    for (int k0 = 0; k0 < KT; k0 += 32) {
        __syncthreads();
        {
            const __bf16* wsrc = W + (size_t)srow * KT + k0 + selt;
            bf16x8 w0 = *(const bf16x8*)wsrc;
            bf16x8 w1 = *(const bf16x8*)(wsrc + 8);
            *(bf16x8*)&lds[srow * 40 + selt] = w0;
            *(bf16x8*)&lds[srow * 40 + selt + 8] = w1;
        }
        bf16x8 a0, a1;
        if constexpr (A_F32) {
            const float* p0 = Af + (size_t)mm0 * KT + k0 + quad * 8;
            const float* p1 = Af + (size_t)mm1 * KT + k0 + quad * 8;
            f32x4 x0 = *(const f32x4*)p0, x1 = *(const f32x4*)(p0 + 4);
            f32x4 y0 = *(const f32x4*)p1, y1 = *(const f32x4*)(p1 + 4);
#pragma unroll
            for (int j = 0; j < 4; j++) { a0[j] = (__bf16)x0[j]; a0[j + 4] = (__bf16)x1[j]; }
#pragma unroll
            for (int j = 0; j < 4; j++) { a1[j] = (__bf16)y0[j]; a1[j + 4] = (__bf16)y1[j]; }
        } else {
            if (k0 < K1) {
                a0 = *(const bf16x8*)(Ab + (size_t)mm0 * K1 + k0 + quad * 8);
                a1 = *(const bf16x8*)(Ab + (size_t)mm1 * K1 + k0 + quad * 8);
            } else {
                a0 = *(const bf16x8*)(A2 + (size_t)mm0 * 128 + (k0 - K1) + quad * 8);
                a1 = *(const bf16x8*)(A2 + (size_t)mm1 * 128 + (k0 - K1) + quad * 8);
            }
        }
        __syncthreads();
#pragma unroll
        for (int nt = 0; nt < 8; nt++) {
            bf16x8 b = *(const bf16x8*)&lds[(nt * 16 + r) * 40 + quad * 8];
            acc[0][nt] = __builtin_amdgcn_mfma_f32_16x16x32_bf16(a0, b, acc[0][nt], 0, 0, 0);
            acc[1][nt] = __builtin_amdgcn_mfma_f32_16x16x32_bf16(a1, b, acc[1][nt], 0, 0, 0);
        }
    }

#pragma unroll
    for (int sub = 0; sub < 2; sub++) {
#pragma unroll
        for (int nt = 0; nt < 8; nt++) {
            int n = nt * 16 + r;
            float bv = bias[n];
#pragma unroll
            for (int i = 0; i < 4; i++) {
                int row = mbase + sub * 16 + quad * 4 + i;
                if (row >= M) continue;
                size_t idx = (size_t)row * HID + n;
                float v;
                if constexpr (SAGE) v = fmaxf(H[idx] + (acc[sub][nt][i] + bv) * scale, 0.f);
                else                v = fmaxf(acc[sub][nt][i] + bv, 0.f);
                H[idx] = v;
                Hbf[idx] = (__bf16)v;
            }
        }
    }
}

// ---------------- driver ----------------

extern "C" void kernel_launch(void* const* d_in, const int* in_sizes, int n_in,
                              void* d_out, int out_size, void* d_ws, size_t ws_size,
                              hipStream_t stream)
{
    (void)in_sizes; (void)n_in; (void)out_size; (void)ws_size;

    const float* x_gene = (const float*)d_in[0];
    const float* x_path = (const float*)d_in[1];
    const float* x_vacc = (const float*)d_in[2];
    const float* win_g  = (const float*)d_in[3];
    const float* bin_g  = (const float*)d_in[4];
    const float* win_p  = (const float*)d_in[5];
    const float* bin_p  = (const float*)d_in[6];
    const float* win_v  = (const float*)d_in[7];
    const float* bin_v  = (const float*)d_in[8];
    const float* wsl    = (const float*)d_in[9];
    const float* bsl    = (const float*)d_in[10];
    const float* wsr    = (const float*)d_in[11];
    const int* ei_tg  = (const int*)d_in[12];
    const int* ei_ing = (const int*)d_in[13];
    const int* ei_ct  = (const int*)d_in[14];
    const int* ei_ii  = (const int*)d_in[15];

    char* p = (char*)d_ws;
    auto alloc = [&](size_t b) { char* r = p; p += (b + 255) & ~((size_t)255); return r; };

    float*    H    = (float*)alloc((size_t)N_TOT * HID * 4);
    _Float16* BASE = (_Float16*)alloc((size_t)OV * HID * 2);
    __bf16*   Hbf  = (__bf16*)alloc((size_t)N_TOT * HID * 2);
    _Float16* Z1   = (_Float16*)alloc((size_t)OV * HID * 2);
    _Float16* Z2   = (_Float16*)alloc((size_t)OV * HID * 2);
    __bf16* AGG_G = (__bf16*)alloc((size_t)N_GENE * 384 * 2);
    __bf16* AGG_P = (__bf16*)alloc((size_t)N_PATH * 128 * 2);
    float* dinv   = (float*)alloc((size_t)N_TOT * 4);
    int* r_rows[4], *r_off[4];
    for (int r = 0; r < 4; r++) r_rows[r] = (int*)alloc((size_t)E_PER * 4);
    r_off[0] = (int*)alloc((size_t)(N_GENE + 1) * 4);
    r_off[1] = (int*)alloc((size_t)(N_PATH + 1) * 4);
    r_off[2] = (int*)alloc((size_t)(N_GENE + 1) * 4);
    r_off[3] = (int*)alloc((size_t)(N_GENE + 1) * 4);
    float* w1 = (float*)alloc((size_t)E_PER * 4);
    float* w2 = (float*)alloc((size_t)E_PER * 4);
    float* w3 = (float*)alloc((size_t)E_PER * 4);
    int* rank = (int*)alloc((size_t)4 * E_PER * 4);
    int* partials = (int*)alloc((size_t)4 * 32 * 4);
    __bf16* wbf_g = (__bf16*)alloc((size_t)HID * 256 * 2);
    __bf16* wbf_p = (__bf16*)alloc((size_t)HID * 128 * 2);
    __bf16* wbf_v = (__bf16*)alloc((size_t)HID * 64 * 2);
    __bf16* Wg[2]; __bf16* Wp[2]; float* bg[2]; float* bp[2];
    for (int l = 0; l < 2; l++) {
        Wg[l] = (__bf16*)alloc((size_t)128 * 512 * 2);
        Wp[l] = (__bf16*)alloc((size_t)128 * 256 * 2);
        bg[l] = (float*)alloc(128 * 4);
        bp[l] = (float*)alloc(128 * 4);
    }
    char* zb = p;
    int* cnt = (int*)alloc((size_t)CNT_TOTAL * 4);
    hipMemsetAsync(zb, 0, (size_t)(p - zb), stream);

    Off4 offs;
    offs.p[0] = r_off[0]; offs.p[1] = r_off[1]; offs.p[2] = r_off[2]; offs.p[3] = r_off[3];

    const int GE = (E_PER + 255) / 256;
    const int TB_G = (N_GENE + 127) / 128;
    const int TB_P = (N_PATH + 127) / 128;
    const int TB_V = (N_VACC + 127) / 128;

    // --- weight prep (1 launch) ---
    prep_all_kernel<<<dim3(256, 3), 256, 0, stream>>>(win_g, win_p, win_v, wbf_g, wbf_p, wbf_v,
                                                      wsl, bsl, wsr, Wg[0], Wg[1], Wp[0], Wp[1],
                                                      bg[0], bg[1], bp[0], bp[1]);

    // --- CSR build: count(+rank) -> scan -> dinv -> fill(no atomics) -> edge weights ---
    Cnt4 c4;
    c4.s[0] = {ei_tg + E_PER,  cnt + 0};
    c4.s[1] = {ei_ing + E_PER, cnt + 50000};
    c4.s[2] = {ei_ct + E_PER,  cnt + 70000};
    c4.s[3] = {ei_ii + E_PER,  cnt + 120000};
    count4_kernel<<<dim3(GE, 4), 256, 0, stream>>>(c4, rank);

    dim3 sg((N_GENE + 4095) / 4096, 4);
    scan1_kernel<<<sg, 256, 0, stream>>>(cnt, partials);
    scan2_kernel<<<1, 64, 0, stream>>>(partials, offs);
    scan3_kernel<<<sg, 256, 0, stream>>>(cnt, partials, offs);

    dinv_kernel<<<(N_TOT + 255) / 256, 256, 0, stream>>>(r_off[0], r_off[1], r_off[2], r_off[3], dinv);

    F4 f4;
    f4.s[0] = {ei_tg,  r_off[0], r_rows[0], OV};   // global vaccine ids
    f4.s[1] = {ei_ing, r_off[1], r_rows[1], OG};
    f4.s[2] = {ei_ct,  r_off[2], r_rows[2], OP};   // global pathway ids
    f4.s[3] = {ei_ii,  r_off[3], r_rows[3], OG};
    fill4_kernel<<<dim3(GE, 4), 256, 0, stream>>>(f4, rank);

    W3 w3s;
    w3s.s[0] = {r_rows[1], w1};
    w3s.s[1] = {r_rows[2], w2};
    w3s.s[2] = {r_rows[3], w3};
    wts3_kernel<<<dim3(GE, 3), 256, 0, stream>>>(w3s, dinv);

    // --- input projections ---
    tgemm_kernel<256, true, false><<<TB_G, 256, 0, stream>>>(x_gene, nullptr, wbf_g, bin_g, 1.f, H, Hbf, N_GENE);
    tgemm_kernel<128, true, false><<<TB_P, 256, 0, stream>>>(x_path, nullptr, wbf_p, bin_p, 1.f,
                                                             H + (size_t)OP * HID, Hbf + (size_t)OP * HID, N_PATH);
    tgemm_kernel< 64, true, false><<<TB_V, 256, 0, stream>>>(x_vacc, nullptr, wbf_v, bin_v, 1.f,
                                                             H + (size_t)OV * HID, Hbf + (size_t)OV * HID, N_VACC);

    // --- 2 hetero-SAGE layers ---
    for (int l = 0; l < 2; l++) {
        Agg4 ag;
        ag.s[0] = {r_rows[0], r_off[0], AGG_G + 0,   384, N_GENE};
        ag.s[1] = {r_rows[2], r_off[2], AGG_G + 128, 384, N_GENE};
        ag.s[2] = {r_rows[3], r_off[3], AGG_G + 256, 384, N_GENE};
        ag.s[3] = {r_rows[1], r_off[1], AGG_P,       128, N_PATH};
        agg_all_kernel<<<dim3(N_GENE / 8, 4), 256, 0, stream>>>(ag, Hbf);
        tgemm_kernel<512, false, true><<<TB_G, 256, 0, stream>>>(AGG_G, Hbf, Wg[l], bg[l], 1.0f / 3.0f,
                                                                 H, Hbf, N_GENE);
        tgemm_kernel<256, false, true><<<TB_P, 256, 0, stream>>>(AGG_P, Hbf + (size_t)OP * HID, Wp[l], bp[l], 1.0f,
                                                                 H + (size_t)OP * HID, Hbf + (size_t)OP * HID, N_PATH);
    }

    // --- APPNP over genes+pathways only (vaccine rows are fixpoints, written by base) ---
    float* dout = (float*)d_out;
    base_kernel<<<N_TOT / 8, 256, 0, stream>>>(H, r_rows[0], r_off[0], dinv, BASE, Z1, dout);

    Csr c1 = {r_off[1], r_rows[1], w1};
    Csr c2 = {r_off[2], r_rows[2], w2};
    Csr c3 = {r_off[3], r_rows[3], w3};
    const int GA = OV / 8;
    appnp_kernel<<<GA, 256, 0, stream>>>(Z1, Z2, BASE, c1, c2, c3, dinv);
    appnp_kernel<<<GA, 256, 0, stream>>>(Z2, Z1, BASE, c1, c2, c3, dinv);
    appnp_kernel<<<GA, 256, 0, stream>>>(Z1, Z2, BASE, c1, c2, c3, dinv);
    appnp_kernel<<<GA, 256, 0, stream>>>(Z2, Z1, BASE, c1, c2, c3, dinv);
    appnp_kernel<<<GA, 256, 0, stream>>>(Z1, Z2, BASE, c1, c2, c3, dinv);
    appnp_kernel<<<GA, 256, 0, stream>>>(Z2, Z1, BASE, c1, c2, c3, dinv);
    appnp_kernel<<<GA, 256, 0, stream>>>(Z1, Z2, BASE, c1, c2, c3, dinv);
    appnp_kernel<<<GA, 256, 0, stream>>>(Z2, dout, BASE, c1, c2, c3, dinv);
}

// Round 7
// 791.588 us; speedup vs baseline: 3.0558x; 1.0723x over previous
//
#include <hip/hip_runtime.h>

#define N_GENE 50000
#define N_PATH 20000
#define N_VACC 10000
#define N_TOT  80000
#define HID    128
#define E_PER  250000
#define OG 0
#define OP 50000
#define OV 70000

typedef __bf16    bf16x8 __attribute__((ext_vector_type(8)));
typedef __bf16    bf16x4 __attribute__((ext_vector_type(4)));
typedef _Float16  f16x4  __attribute__((ext_vector_type(4)));
typedef float     f32x4  __attribute__((ext_vector_type(4)));

__constant__ int c_segn[4] = {N_GENE, N_PATH, N_GENE, N_GENE};
__constant__ int c_segb[4] = {0, 50000, 70000, 120000};
#define CNT_TOTAL 170000

struct Off4 { int* p[4]; };
struct CntSeg { const int* dst; int* cnt; };
struct Cnt4 { CntSeg s[4]; };
struct F4Seg { const int* ei; const int* off; int* rows; int2* pk; int soff; };
struct F4 { F4Seg s[4]; };
struct AggSeg { const int* rows; const int* off; __bf16* out; int ldo; int n; };
struct Agg4 { AggSeg s[4]; };
struct CsrP { const int* off; const int2* pk; };

// ---------------- CSR build ----------------

__global__ void count4_kernel(Cnt4 a, int* __restrict__ rank)
{
    int seg = blockIdx.y;
    int e = blockIdx.x * 256 + threadIdx.x;
    if (e < E_PER) rank[seg * E_PER + e] = atomicAdd(&a.s[seg].cnt[a.s[seg].dst[e]], 1);
}

__global__ void scan1_kernel(const int* __restrict__ cnt, int* __restrict__ partials)
{
    int seg = blockIdx.y, blk = blockIdx.x;
    int n = c_segn[seg];
    if (blk >= ((n + 4095) >> 12)) return;
    const int* base = cnt + c_segb[seg];
    int t = threadIdx.x;
    int i0 = (blk << 12) + t * 16;
    int s = 0;
#pragma unroll
    for (int j = 0; j < 16; j++) { int i = i0 + j; if (i < n) s += base[i]; }
    __shared__ int sh[256];
    sh[t] = s; __syncthreads();
    for (int d = 128; d; d >>= 1) { if (t < d) sh[t] += sh[t + d]; __syncthreads(); }
    if (t == 0) partials[seg * 32 + blk] = sh[0];
}

__global__ void scan2_kernel(int* __restrict__ partials, Off4 offs)
{
    int s = threadIdx.x;
    if (s < 4) {
        int n = c_segn[s];
        int nb = (n + 4095) >> 12;
        int run = 0;
        for (int b = 0; b < nb; b++) { int v = partials[s * 32 + b]; partials[s * 32 + b] = run; run += v; }
        offs.p[s][n] = run;
    }
}

__global__ void scan3_kernel(const int* __restrict__ cnt, const int* __restrict__ partials, Off4 offs)
{
    int seg = blockIdx.y, blk = blockIdx.x;
    int n = c_segn[seg];
    if (blk >= ((n + 4095) >> 12)) return;
    const int* base = cnt + c_segb[seg];
    int* off = offs.p[seg];
    int t = threadIdx.x;
    int i0 = (blk << 12) + t * 16;
    int loc[16];
    int s = 0;
#pragma unroll
    for (int j = 0; j < 16; j++) { int i = i0 + j; int v = (i < n) ? base[i] : 0; loc[j] = s; s += v; }
    __shared__ int sh[256];
    sh[t] = s; __syncthreads();
    for (int d = 1; d < 256; d <<= 1) {
        int v = (t >= d) ? sh[t - d] : 0; __syncthreads();
        sh[t] += v; __syncthreads();
    }
    int base_off = sh[t] - s + partials[seg * 32 + blk];
#pragma unroll
    for (int j = 0; j < 16; j++) { int i = i0 + j; if (i < n) off[i] = base_off + loc[j]; }
}

__global__ void dinv_kernel(const int* __restrict__ r0, const int* __restrict__ r1,
                            const int* __restrict__ r2, const int* __restrict__ r3,
                            float* __restrict__ dinv)
{
    int i = blockIdx.x * 256 + threadIdx.x;
    if (i >= N_TOT) return;
    int deg = 1;
    if (i < N_GENE) deg += (r0[i + 1] - r0[i]) + (r2[i + 1] - r2[i]) + (r3[i + 1] - r3[i]);
    else if (i < OV) { int k = i - OP; deg += r1[k + 1] - r1[k]; }
    dinv[i] = rsqrtf((float)deg);
}

// non-atomic fill; stores GLOBAL src ids; also writes packed (src, dinv[src]) for appnp segs
__global__ void fill4_kernel(F4 a, const int* __restrict__ rank, const float* __restrict__ dinv)
{
    int seg = blockIdx.y;
    int e = blockIdx.x * 256 + threadIdx.x;
    if (e >= E_PER) return;
    const int* ei = a.s[seg].ei;
    int s = ei[e] + a.s[seg].soff;
    int d = ei[E_PER + e];
    int pos = a.s[seg].off[d] + rank[seg * E_PER + e];
    a.s[seg].rows[pos] = s;
    if (a.s[seg].pk) a.s[seg].pk[pos] = make_int2(s, __float_as_int(dinv[s]));
}

// ---------------- gather kernels (32 lanes/node, 8 nodes/block) ----------------

__global__ void agg_all_kernel(Agg4 a, const __bf16* __restrict__ Hbf)
{
    int seg = blockIdx.y;
    int t = threadIdx.x;
    int node = blockIdx.x * 8 + (t >> 5);
    if (node >= a.s[seg].n) return;
    const int* rows = a.s[seg].rows;
    int sub = t & 31;
    int s = a.s[seg].off[node], e = a.s[seg].off[node + 1];
    f32x4 A0 = {0,0,0,0}, A1 = {0,0,0,0}, A2v = {0,0,0,0}, A3 = {0,0,0,0};
    int i = s;
    for (; i + 4 <= e; i += 4) {
        int r0 = rows[i], r1 = rows[i + 1], r2 = rows[i + 2], r3 = rows[i + 3];
        bf16x4 x0 = *(const bf16x4*)&Hbf[(size_t)r0 * HID + sub * 4];
        bf16x4 x1 = *(const bf16x4*)&Hbf[(size_t)r1 * HID + sub * 4];
        bf16x4 x2 = *(const bf16x4*)&Hbf[(size_t)r2 * HID + sub * 4];
        bf16x4 x3 = *(const bf16x4*)&Hbf[(size_t)r3 * HID + sub * 4];
#pragma unroll
        for (int j = 0; j < 4; j++) {
            A0[j] += (float)x0[j]; A1[j] += (float)x1[j];
            A2v[j] += (float)x2[j]; A3[j] += (float)x3[j];
        }
    }
    for (; i < e; i++) {
        bf16x4 x = *(const bf16x4*)&Hbf[(size_t)rows[i] * HID + sub * 4];
#pragma unroll
        for (int j = 0; j < 4; j++) A0[j] += (float)x[j];
    }
    f32x4 acc = (A0 + A1) + (A2v + A3);
    float inv = (e > s) ? 1.0f / (float)(e - s) : 0.0f;
    bf16x4 o;
    o[0] = (__bf16)(acc[0] * inv); o[1] = (__bf16)(acc[1] * inv);
    o[2] = (__bf16)(acc[2] * inv); o[3] = (__bf16)(acc[3] * inv);
    *(bf16x4*)&a.s[seg].out[(size_t)node * a.s[seg].ldo + sub * 4] = o;
}

// base = fp16(0.1*H + genes: 0.9*dinv*sum_{v->g} h_v); z0 = fp16(H); vaccine rows -> dout (fixpoint)
__global__ void base_kernel(const float* __restrict__ H, const int* __restrict__ r0rows,
                            const int* __restrict__ r0off, const float* __restrict__ dinv,
                            _Float16* __restrict__ base, _Float16* __restrict__ z0,
                            float* __restrict__ dout)
{
    int t = threadIdx.x;
    int node = blockIdx.x * 8 + (t >> 5);
    int sub = t & 31;
    size_t idx = (size_t)node * HID + sub * 4;
    f32x4 h = *(const f32x4*)&H[idx];
    if (node >= OV) { *(f32x4*)&dout[idx] = h; return; }
    f32x4 acc = {0.f, 0.f, 0.f, 0.f};
    if (node < N_GENE) {
        for (int i = r0off[node]; i < r0off[node + 1]; i++) {
            acc += *(const f32x4*)&H[(size_t)r0rows[i] * HID + sub * 4];
        }
        acc *= 0.9f * dinv[node];
    }
    f32x4 b = h * 0.1f + acc;
    f16x4 bo, z;
    bo[0] = (_Float16)b[0]; bo[1] = (_Float16)b[1]; bo[2] = (_Float16)b[2]; bo[3] = (_Float16)b[3];
    z[0] = (_Float16)h[0]; z[1] = (_Float16)h[1]; z[2] = (_Float16)h[2]; z[3] = (_Float16)h[3];
    *(f16x4*)&base[idx] = bo;
    *(f16x4*)&z0[idx] = z;
}

__device__ __forceinline__ void gathp(const int* __restrict__ off, const int2* __restrict__ pk,
                                      int node, int sub, const _Float16* __restrict__ zin,
                                      f32x4& A0, f32x4& A1, f32x4& A2v, f32x4& A3)
{
    int s = off[node], e = off[node + 1];
    int i = s;
    for (; i + 4 <= e; i += 4) {
        int2 p0 = pk[i], p1 = pk[i + 1], p2 = pk[i + 2], p3 = pk[i + 3];
        f16x4 x0 = *(const f16x4*)&zin[(size_t)p0.x * HID + sub * 4];
        f16x4 x1 = *(const f16x4*)&zin[(size_t)p1.x * HID + sub * 4];
        f16x4 x2 = *(const f16x4*)&zin[(size_t)p2.x * HID + sub * 4];
        f16x4 x3 = *(const f16x4*)&zin[(size_t)p3.x * HID + sub * 4];
        float w0 = __int_as_float(p0.y), w1 = __int_as_float(p1.y);
        float w2 = __int_as_float(p2.y), w3 = __int_as_float(p3.y);
#pragma unroll
        for (int j = 0; j < 4; j++) {
            A0[j] += (float)x0[j] * w0; A1[j] += (float)x1[j] * w1;
            A2v[j] += (float)x2[j] * w2; A3[j] += (float)x3[j] * w3;
        }
    }
    for (; i < e; i++) {
        int2 p = pk[i];
        float w = __int_as_float(p.y);
        f16x4 x = *(const f16x4*)&zin[(size_t)p.x * HID + sub * 4];
#pragma unroll
        for (int j = 0; j < 4; j++) A0[j] += (float)x[j] * w;
    }
}

// columns [0, 70000); vaccine columns are fixpoints handled in base_kernel
template<typename OT>
__launch_bounds__(256)
__global__ void appnp_kernel(const _Float16* __restrict__ zin, OT* __restrict__ zout,
                             const _Float16* __restrict__ base,
                             CsrP c1, CsrP c2, CsrP c3, const float* __restrict__ dinv)
{
    int t = threadIdx.x;
    int c = blockIdx.x * 8 + (t >> 5);
    int sub = t & 31;
    f32x4 A0 = {0,0,0,0}, A1 = {0,0,0,0}, A2v = {0,0,0,0}, A3 = {0,0,0,0};
    if (c < OP) {
        gathp(c2.off, c2.pk, c, sub, zin, A0, A1, A2v, A3);
        gathp(c3.off, c3.pk, c, sub, zin, A0, A1, A2v, A3);
    } else {
        gathp(c1.off, c1.pk, c - OP, sub, zin, A0, A1, A2v, A3);
    }
    f32x4 acc = (A0 + A1) + (A2v + A3);
    float dc = dinv[c];
    size_t idx = (size_t)c * HID + sub * 4;
    f16x4 zi = *(const f16x4*)&zin[idx];
    f16x4 bs = *(const f16x4*)&base[idx];
    f32x4 res;
    float d2 = dc * dc;
#pragma unroll
    for (int j = 0; j < 4; j++) res[j] = 0.9f * (dc * acc[j] + d2 * (float)zi[j]) + (float)bs[j];
    if constexpr (sizeof(OT) == 2) {
        f16x4 o;
        o[0] = (_Float16)res[0]; o[1] = (_Float16)res[1]; o[2] = (_Float16)res[2]; o[3] = (_Float16)res[3];
        *(f16x4*)&zout[idx] = o;
    } else {
        *(f32x4*)&zout[idx] = res;
    }
}

// ---------------- weight prep ----------------

__global__ void prep_all_kernel(const float* __restrict__ wg, const float* __restrict__ wp,
                                const float* __restrict__ wv,
                                __bf16* __restrict__ obg, __bf16* __restrict__ obp, __bf16* __restrict__ obv,
                                const float* __restrict__ wsl, const float* __restrict__ bsl,
                                const float* __restrict__ wsr,
                                __bf16* __restrict__ Wg0, __bf16* __restrict__ Wg1,
                                __bf16* __restrict__ Wp0, __bf16* __restrict__ Wp1,
                                float* __restrict__ bg0, float* __restrict__ bg1,
                                float* __restrict__ bp0, float* __restrict__ bp1)
{
    int y = blockIdx.y;
    int i = blockIdx.x * 256 + threadIdx.x;
    if (y == 0) {
        if (i < 32768) obg[i] = (__bf16)wg[i];
        if (i < 16384) obp[i] = (__bf16)wp[i];
        if (i < 8192)  obv[i] = (__bf16)wv[i];
        return;
    }
    int layer = y - 1;
    const float* WL = wsl + (size_t)layer * 4 * HID * HID;
    const float* WR = wsr + (size_t)layer * 4 * HID * HID;
    __bf16* Wg = layer ? Wg1 : Wg0;
    __bf16* Wp = layer ? Wp1 : Wp0;
    float* bg = layer ? bg1 : bg0;
    float* bp = layer ? bp1 : bp0;
    if (i < 128 * 512) {
        int nr = i >> 9, k = i & 511;
        float v;
        if (k < 128)      v = WL[0 * 16384 + nr * 128 + k];
        else if (k < 256) v = WL[2 * 16384 + nr * 128 + (k - 128)];
        else if (k < 384) v = WL[3 * 16384 + nr * 128 + (k - 256)];
        else {
            int kk = k - 384;
            v = WR[0 * 16384 + nr * 128 + kk] + WR[2 * 16384 + nr * 128 + kk] + WR[3 * 16384 + nr * 128 + kk];
        }
        Wg[i] = (__bf16)v;
    }
    if (i < 128 * 256) {
        int nr = i >> 8, k = i & 255;
        float v = (k < 128) ? WL[1 * 16384 + nr * 128 + k] : WR[1 * 16384 + nr * 128 + (k - 128)];
        Wp[i] = (__bf16)v;
    }
    if (i < 128) {
        const float* BL = bsl + (size_t)layer * 4 * HID;
        bg[i] = BL[0 * 128 + i] + BL[2 * 128 + i] + BL[3 * 128 + i];
        bp[i] = BL[1 * 128 + i];
    }
}

// ---------------- segmented tiled MFMA GEMM (multiple GEMMs per dispatch) ----------------
// block = 128 rows (4 waves x 32 rows), K chunked by 32, W chunk (8 KB) in LDS stride 40.
// layouts verified r2-r6: A[m=lane&15][k=quad*8+j]; B: n=lane&15, same k slice; C/D: col=lane&15, row=quad*4+reg.

struct GemmSeg {
    int blk0, M, KT, K1;          // K1==KT -> no A2 tail
    const void* A1; const __bf16* A2;
    const __bf16* W; const float* bias;
    float scale;
    float* H; __bf16* Hbf;
    int a_f32, sage;
};
template<int NSEG> struct GemmSegs { GemmSeg s[NSEG]; };

template<int NSEG>
__launch_bounds__(256)
__global__ void tgemm_multi(GemmSegs<NSEG> segs)
{
    int si = 0;
#pragma unroll
    for (int k = 1; k < NSEG; k++) if ((int)blockIdx.x >= segs.s[k].blk0) si = k;
    GemmSeg sg = segs.s[si];

    __shared__ __bf16 lds[128 * 40];
    int t = threadIdx.x;
    int wave = t >> 6, lane = t & 63;
    int r = lane & 15, quad = lane >> 4;
    int mbase = (blockIdx.x - sg.blk0) * 128 + wave * 32;
    int M = sg.M, KT = sg.KT, K1 = sg.K1;
    int mm0 = min(mbase + r, M - 1);
    int mm1 = min(mbase + 16 + r, M - 1);
    const float* Af = (const float*)sg.A1;
    const __bf16* Ab = (const __bf16*)sg.A1;

    f32x4 acc[2][8];
#pragma unroll
    for (int s = 0; s < 2; s++)
#pragma unroll
        for (int n = 0; n < 8; n++) acc[s][n] = (f32x4){0.f, 0.f, 0.f, 0.f};

    int srow = t >> 1;
    int selt = (t & 1) * 16;

    for (int k0 = 0; k0 < KT; k0 += 32) {
        __syncthreads();
        {
            const __bf16* wsrc = sg.W + (size_t)srow * KT + k0 + selt;
            bf16x8 w0 = *(const bf16x8*)wsrc;
            bf16x8 w1 = *(const bf16x8*)(wsrc + 8);
            *(bf16x8*)&lds[srow * 40 + selt] = w0;
            *(bf16x8*)&lds[srow * 40 + selt + 8] = w1;
        }
        bf16x8 a0, a1;
        if (sg.a_f32) {
            const float* p0 = Af + (size_t)mm0 * KT + k0 + quad * 8;
            const float* p1 = Af + (size_t)mm1 * KT + k0 + quad * 8;
            f32x4 x0 = *(const f32x4*)p0, x1 = *(const f32x4*)(p0 + 4);
            f32x4 y0 = *(const f32x4*)p1, y1 = *(const f32x4*)(p1 + 4);
#pragma unroll
            for (int j = 0; j < 4; j++) { a0[j] = (__bf16)x0[j]; a0[j + 4] = (__bf16)x1[j]; }
#pragma unroll
            for (int j = 0; j < 4; j++) { a1[j] = (__bf16)y0[j]; a1[j + 4] = (__bf16)y1[j]; }
        } else if (k0 < K1) {
            a0 = *(const bf16x8*)(Ab + (size_t)mm0 * K1 + k0 + quad * 8);
            a1 = *(const bf16x8*)(Ab + (size_t)mm1 * K1 + k0 + quad * 8);
        } else {
            a0 = *(const bf16x8*)(sg.A2 + (size_t)mm0 * 128 + (k0 - K1) + quad * 8);
            a1 = *(const bf16x8*)(sg.A2 + (size_t)mm1 * 128 + (k0 - K1) + quad * 8);
        }
        __syncthreads();
#pragma unroll
        for (int nt = 0; nt < 8; nt++) {
            bf16x8 b = *(const bf16x8*)&lds[(nt * 16 + r) * 40 + quad * 8];
            acc[0][nt] = __builtin_amdgcn_mfma_f32_16x16x32_bf16(a0, b, acc[0][nt], 0, 0, 0);
            acc[1][nt] = __builtin_amdgcn_mfma_f32_16x16x32_bf16(a1, b, acc[1][nt], 0, 0, 0);
        }
    }

#pragma unroll
    for (int sub = 0; sub < 2; sub++) {
#pragma unroll
        for (int nt = 0; nt < 8; nt++) {
            int n = nt * 16 + r;
            float bv = sg.bias[n];
#pragma unroll
            for (int i = 0; i < 4; i++) {
                int row = mbase + sub * 16 + quad * 4 + i;
                if (row >= M) continue;
                size_t idx = (size_t)row * HID + n;
                float v;
                if (sg.sage) v = fmaxf(sg.H[idx] + (acc[sub][nt][i] + bv) * sg.scale, 0.f);
                else         v = fmaxf(acc[sub][nt][i] + bv, 0.f);
                sg.H[idx] = v;
                sg.Hbf[idx] = (__bf16)v;
            }
        }
    }
}

// ---------------- driver ----------------

extern "C" void kernel_launch(void* const* d_in, const int* in_sizes, int n_in,
                              void* d_out, int out_size, void* d_ws, size_t ws_size,
                              hipStream_t stream)
{
    (void)in_sizes; (void)n_in; (void)out_size; (void)ws_size;

    const float* x_gene = (const float*)d_in[0];
    const float* x_path = (const float*)d_in[1];
    const float* x_vacc = (const float*)d_in[2];
    const float* win_g  = (const float*)d_in[3];
    const float* bin_g  = (const float*)d_in[4];
    const float* win_p  = (const float*)d_in[5];
    const float* bin_p  = (const float*)d_in[6];
    const float* win_v  = (const float*)d_in[7];
    const float* bin_v  = (const float*)d_in[8];
    const float* wsl    = (const float*)d_in[9];
    const float* bsl    = (const float*)d_in[10];
    const float* wsr    = (const float*)d_in[11];
    const int* ei_tg  = (const int*)d_in[12];
    const int* ei_ing = (const int*)d_in[13];
    const int* ei_ct  = (const int*)d_in[14];
    const int* ei_ii  = (const int*)d_in[15];

    char* p = (char*)d_ws;
    auto alloc = [&](size_t b) { char* r = p; p += (b + 255) & ~((size_t)255); return r; };

    float*    H    = (float*)alloc((size_t)N_TOT * HID * 4);
    _Float16* BASE = (_Float16*)alloc((size_t)OV * HID * 2);
    __bf16*   Hbf  = (__bf16*)alloc((size_t)N_TOT * HID * 2);
    _Float16* Z1   = (_Float16*)alloc((size_t)OV * HID * 2);
    _Float16* Z2   = (_Float16*)alloc((size_t)OV * HID * 2);
    __bf16* AGG_G = (__bf16*)alloc((size_t)N_GENE * 384 * 2);
    __bf16* AGG_P = (__bf16*)alloc((size_t)N_PATH * 128 * 2);
    float* dinv   = (float*)alloc((size_t)N_TOT * 4);
    int* r_rows[4], *r_off[4];
    for (int r = 0; r < 4; r++) r_rows[r] = (int*)alloc((size_t)E_PER * 4);
    r_off[0] = (int*)alloc((size_t)(N_GENE + 1) * 4);
    r_off[1] = (int*)alloc((size_t)(N_PATH + 1) * 4);
    r_off[2] = (int*)alloc((size_t)(N_GENE + 1) * 4);
    r_off[3] = (int*)alloc((size_t)(N_GENE + 1) * 4);
    int2* pk1 = (int2*)alloc((size_t)E_PER * 8);
    int2* pk2 = (int2*)alloc((size_t)E_PER * 8);
    int2* pk3 = (int2*)alloc((size_t)E_PER * 8);
    int* rank = (int*)alloc((size_t)4 * E_PER * 4);
    int* partials = (int*)alloc((size_t)4 * 32 * 4);
    __bf16* wbf_g = (__bf16*)alloc((size_t)HID * 256 * 2);
    __bf16* wbf_p = (__bf16*)alloc((size_t)HID * 128 * 2);
    __bf16* wbf_v = (__bf16*)alloc((size_t)HID * 64 * 2);
    __bf16* Wg[2]; __bf16* Wp[2]; float* bg[2]; float* bp[2];
    for (int l = 0; l < 2; l++) {
        Wg[l] = (__bf16*)alloc((size_t)128 * 512 * 2);
        Wp[l] = (__bf16*)alloc((size_t)128 * 256 * 2);
        bg[l] = (float*)alloc(128 * 4);
        bp[l] = (float*)alloc(128 * 4);
    }
    char* zb = p;
    int* cnt = (int*)alloc((size_t)CNT_TOTAL * 4);
    hipMemsetAsync(zb, 0, (size_t)(p - zb), stream);

    Off4 offs;
    offs.p[0] = r_off[0]; offs.p[1] = r_off[1]; offs.p[2] = r_off[2]; offs.p[3] = r_off[3];

    const int GE = (E_PER + 255) / 256;
    const int TB_G = (N_GENE + 127) / 128;   // 391
    const int TB_P = (N_PATH + 127) / 128;   // 157
    const int TB_V = (N_VACC + 127) / 128;   // 79

    prep_all_kernel<<<dim3(256, 3), 256, 0, stream>>>(win_g, win_p, win_v, wbf_g, wbf_p, wbf_v,
                                                      wsl, bsl, wsr, Wg[0], Wg[1], Wp[0], Wp[1],
                                                      bg[0], bg[1], bp[0], bp[1]);

    Cnt4 c4;
    c4.s[0] = {ei_tg + E_PER,  cnt + 0};
    c4.s[1] = {ei_ing + E_PER, cnt + 50000};
    c4.s[2] = {ei_ct + E_PER,  cnt + 70000};
    c4.s[3] = {ei_ii + E_PER,  cnt + 120000};
    count4_kernel<<<dim3(GE, 4), 256, 0, stream>>>(c4, rank);

    dim3 sg((N_GENE + 4095) / 4096, 4);
    scan1_kernel<<<sg, 256, 0, stream>>>(cnt, partials);
    scan2_kernel<<<1, 64, 0, stream>>>(partials, offs);
    scan3_kernel<<<sg, 256, 0, stream>>>(cnt, partials, offs);

    dinv_kernel<<<(N_TOT + 255) / 256, 256, 0, stream>>>(r_off[0], r_off[1], r_off[2], r_off[3], dinv);

    F4 f4;
    f4.s[0] = {ei_tg,  r_off[0], r_rows[0], nullptr, OV};
    f4.s[1] = {ei_ing, r_off[1], r_rows[1], pk1,     OG};
    f4.s[2] = {ei_ct,  r_off[2], r_rows[2], pk2,     OP};
    f4.s[3] = {ei_ii,  r_off[3], r_rows[3], pk3,     OG};
    fill4_kernel<<<dim3(GE, 4), 256, 0, stream>>>(f4, rank, dinv);

    // --- input projections: one dispatch, 3 segments ---
    GemmSegs<3> gp;
    gp.s[0] = {0,           N_GENE, 256, 256, x_gene, nullptr, wbf_g, bin_g, 1.f, H, Hbf, 1, 0};
    gp.s[1] = {TB_G,        N_PATH, 128, 128, x_path, nullptr, wbf_p, bin_p, 1.f,
               H + (size_t)OP * HID, Hbf + (size_t)OP * HID, 1, 0};
    gp.s[2] = {TB_G + TB_P, N_VACC,  64,  64, x_vacc, nullptr, wbf_v, bin_v, 1.f,
               H + (size_t)OV * HID, Hbf + (size_t)OV * HID, 1, 0};
    tgemm_multi<3><<<TB_G + TB_P + TB_V, 256, 0, stream>>>(gp);

    // --- 2 hetero-SAGE layers: agg (1 dispatch) + gemm (1 dispatch) each ---
    for (int l = 0; l < 2; l++) {
        Agg4 ag;
        ag.s[0] = {r_rows[0], r_off[0], AGG_G + 0,   384, N_GENE};
        ag.s[1] = {r_rows[2], r_off[2], AGG_G + 128, 384, N_GENE};
        ag.s[2] = {r_rows[3], r_off[3], AGG_G + 256, 384, N_GENE};
        ag.s[3] = {r_rows[1], r_off[1], AGG_P,       128, N_PATH};
        agg_all_kernel<<<dim3(N_GENE / 8, 4), 256, 0, stream>>>(ag, Hbf);

        GemmSegs<2> gs;
        gs.s[0] = {0,    N_GENE, 512, 384, AGG_G, Hbf, Wg[l], bg[l], 1.0f / 3.0f, H, Hbf, 0, 1};
        gs.s[1] = {TB_G, N_PATH, 256, 128, AGG_P, Hbf + (size_t)OP * HID, Wp[l], bp[l], 1.0f,
                   H + (size_t)OP * HID, Hbf + (size_t)OP * HID, 0, 1};
        tgemm_multi<2><<<TB_G + TB_P, 256, 0, stream>>>(gs);
    }

    // --- APPNP over genes+pathways (vaccine rows fixpoint, written by base) ---
    float* dout = (float*)d_out;
    base_kernel<<<N_TOT / 8, 256, 0, stream>>>(H, r_rows[0], r_off[0], dinv, BASE, Z1, dout);

    CsrP c1 = {r_off[1], pk1};
    CsrP c2 = {r_off[2], pk2};
    CsrP c3 = {r_off[3], pk3};
    const int GA = OV / 8;
    appnp_kernel<<<GA, 256, 0, stream>>>(Z1, Z2, BASE, c1, c2, c3, dinv);
    appnp_kernel<<<GA, 256, 0, stream>>>(Z2, Z1, BASE, c1, c2, c3, dinv);
    appnp_kernel<<<GA, 256, 0, stream>>>(Z1, Z2, BASE, c1, c2, c3, dinv);
    appnp_kernel<<<GA, 256, 0, stream>>>(Z2, Z1, BASE, c1, c2, c3, dinv);
    appnp_kernel<<<GA, 256, 0, stream>>>(Z1, Z2, BASE, c1, c2, c3, dinv);
    appnp_kernel<<<GA, 256, 0, stream>>>(Z2, Z1, BASE, c1, c2, c3, dinv);
    appnp_kernel<<<GA, 256, 0, stream>>>(Z1, Z2, BASE, c1, c2, c3, dinv);
    appnp_kernel<<<GA, 256, 0, stream>>>(Z2, dout, BASE, c1, c2, c3, dinv);
}

// Round 8
// 722.493 us; speedup vs baseline: 3.3481x; 1.0956x over previous
//
#include <hip/hip_runtime.h>

#define N_GENE 50000
#define N_PATH 20000
#define N_VACC 10000
#define N_TOT  80000
#define HID    128
#define E_PER  250000
#define OG 0
#define OP 50000
#define OV 70000

typedef _Float16  f16x8  __attribute__((ext_vector_type(8)));
typedef _Float16  f16x4  __attribute__((ext_vector_type(4)));
typedef float     f32x4  __attribute__((ext_vector_type(4)));

__constant__ int c_segn[4] = {N_GENE, N_PATH, N_GENE, N_GENE};
__constant__ int c_segb[4] = {0, 50000, 70000, 120000};
#define CNT_TOTAL 170000

struct Off4 { int* p[4]; };
struct CntSeg { const int* dst; int* cnt; };
struct Cnt4 { CntSeg s[4]; };
struct F4Seg { const int* ei; const int* off; int* rows; int2* pk; int soff; };
struct F4 { F4Seg s[4]; };
struct AggSeg { const int* rows; const int* off; _Float16* out; int ldo; int n; };
struct Agg4 { AggSeg s[4]; };
struct CsrP { const int* off; const int2* pk; };

// ---------------- CSR build ----------------

__global__ void count4_kernel(Cnt4 a, int* __restrict__ rank)
{
    int seg = blockIdx.y;
    int e = blockIdx.x * 256 + threadIdx.x;
    if (e < E_PER) rank[seg * E_PER + e] = atomicAdd(&a.s[seg].cnt[a.s[seg].dst[e]], 1);
}

__global__ void scan1_kernel(const int* __restrict__ cnt, int* __restrict__ partials)
{
    int seg = blockIdx.y, blk = blockIdx.x;
    int n = c_segn[seg];
    if (blk >= ((n + 4095) >> 12)) return;
    const int* base = cnt + c_segb[seg];
    int t = threadIdx.x;
    int i0 = (blk << 12) + t * 16;
    int s = 0;
#pragma unroll
    for (int j = 0; j < 16; j++) { int i = i0 + j; if (i < n) s += base[i]; }
    __shared__ int sh[256];
    sh[t] = s; __syncthreads();
    for (int d = 128; d; d >>= 1) { if (t < d) sh[t] += sh[t + d]; __syncthreads(); }
    if (t == 0) partials[seg * 32 + blk] = sh[0];
}

__global__ void scan2_kernel(int* __restrict__ partials, Off4 offs)
{
    int s = threadIdx.x;
    if (s < 4) {
        int n = c_segn[s];
        int nb = (n + 4095) >> 12;
        int run = 0;
        for (int b = 0; b < nb; b++) { int v = partials[s * 32 + b]; partials[s * 32 + b] = run; run += v; }
        offs.p[s][n] = run;
    }
}

__global__ void scan3_kernel(const int* __restrict__ cnt, const int* __restrict__ partials, Off4 offs)
{
    int seg = blockIdx.y, blk = blockIdx.x;
    int n = c_segn[seg];
    if (blk >= ((n + 4095) >> 12)) return;
    const int* base = cnt + c_segb[seg];
    int* off = offs.p[seg];
    int t = threadIdx.x;
    int i0 = (blk << 12) + t * 16;
    int loc[16];
    int s = 0;
#pragma unroll
    for (int j = 0; j < 16; j++) { int i = i0 + j; int v = (i < n) ? base[i] : 0; loc[j] = s; s += v; }
    __shared__ int sh[256];
    sh[t] = s; __syncthreads();
    for (int d = 1; d < 256; d <<= 1) {
        int v = (t >= d) ? sh[t - d] : 0; __syncthreads();
        sh[t] += v; __syncthreads();
    }
    int base_off = sh[t] - s + partials[seg * 32 + blk];
#pragma unroll
    for (int j = 0; j < 16; j++) { int i = i0 + j; if (i < n) off[i] = base_off + loc[j]; }
}

__global__ void dinv_kernel(const int* __restrict__ r0, const int* __restrict__ r1,
                            const int* __restrict__ r2, const int* __restrict__ r3,
                            float* __restrict__ dinv)
{
    int i = blockIdx.x * 256 + threadIdx.x;
    if (i >= N_TOT) return;
    int deg = 1;
    if (i < N_GENE) deg += (r0[i + 1] - r0[i]) + (r2[i + 1] - r2[i]) + (r3[i + 1] - r3[i]);
    else if (i < OV) { int k = i - OP; deg += r1[k + 1] - r1[k]; }
    dinv[i] = rsqrtf((float)deg);
}

// non-atomic fill; stores GLOBAL src ids; packed (src, dinv[src]) for appnp segs
__global__ void fill4_kernel(F4 a, const int* __restrict__ rank, const float* __restrict__ dinv)
{
    int seg = blockIdx.y;
    int e = blockIdx.x * 256 + threadIdx.x;
    if (e >= E_PER) return;
    const int* ei = a.s[seg].ei;
    int s = ei[e] + a.s[seg].soff;
    int d = ei[E_PER + e];
    int pos = a.s[seg].off[d] + rank[seg * E_PER + e];
    a.s[seg].rows[pos] = s;
    if (a.s[seg].pk) a.s[seg].pk[pos] = make_int2(s, __float_as_int(dinv[s]));
}

// ---------------- gather kernels (16 lanes/node, 16 nodes/block, f16x8 = 16B loads) ----------------

__global__ void agg_all_kernel(Agg4 a, const _Float16* __restrict__ Hh)
{
    int seg = blockIdx.y;
    int t = threadIdx.x;
    int node = blockIdx.x * 16 + (t >> 4);
    if (node >= a.s[seg].n) return;
    const int* rows = a.s[seg].rows;
    int sub = t & 15;
    int s = a.s[seg].off[node], e = a.s[seg].off[node + 1];
    float acc0[8] = {}, acc1[8] = {};
    int i = s;
    for (; i + 4 <= e; i += 4) {
        int r0 = rows[i], r1 = rows[i + 1], r2 = rows[i + 2], r3 = rows[i + 3];
        f16x8 x0 = *(const f16x8*)&Hh[(size_t)r0 * HID + sub * 8];
        f16x8 x1 = *(const f16x8*)&Hh[(size_t)r1 * HID + sub * 8];
        f16x8 x2 = *(const f16x8*)&Hh[(size_t)r2 * HID + sub * 8];
        f16x8 x3 = *(const f16x8*)&Hh[(size_t)r3 * HID + sub * 8];
#pragma unroll
        for (int j = 0; j < 8; j++) {
            acc0[j] += (float)x0[j] + (float)x1[j];
            acc1[j] += (float)x2[j] + (float)x3[j];
        }
    }
    for (; i < e; i++) {
        f16x8 x = *(const f16x8*)&Hh[(size_t)rows[i] * HID + sub * 8];
#pragma unroll
        for (int j = 0; j < 8; j++) acc0[j] += (float)x[j];
    }
    float inv = (e > s) ? 1.0f / (float)(e - s) : 0.0f;
    f16x8 o;
#pragma unroll
    for (int j = 0; j < 8; j++) o[j] = (_Float16)((acc0[j] + acc1[j]) * inv);
    *(f16x8*)&a.s[seg].out[(size_t)node * a.s[seg].ldo + sub * 8] = o;
}

// base = fp16(0.1*Hh + genes: 0.9*dinv*sum_{v->g} h_v); z0 = Hh; vaccine rows -> dout (fixpoint)
__global__ void base_kernel(const _Float16* __restrict__ Hh, const int* __restrict__ r0rows,
                            const int* __restrict__ r0off, const float* __restrict__ dinv,
                            _Float16* __restrict__ base, _Float16* __restrict__ z0,
                            float* __restrict__ dout)
{
    int t = threadIdx.x;
    int node = blockIdx.x * 16 + (t >> 4);
    int sub = t & 15;
    size_t idx = (size_t)node * HID + sub * 8;
    f16x8 h = *(const f16x8*)&Hh[idx];
    if (node >= OV) {
        f32x4 o0, o1;
#pragma unroll
        for (int j = 0; j < 4; j++) { o0[j] = (float)h[j]; o1[j] = (float)h[j + 4]; }
        *(f32x4*)&dout[idx] = o0;
        *(f32x4*)&dout[idx + 4] = o1;
        return;
    }
    float acc[8] = {};
    if (node < N_GENE) {
        for (int i = r0off[node]; i < r0off[node + 1]; i++) {
            f16x8 v = *(const f16x8*)&Hh[(size_t)r0rows[i] * HID + sub * 8];
#pragma unroll
            for (int j = 0; j < 8; j++) acc[j] += (float)v[j];
        }
        float sc = 0.9f * dinv[node];
#pragma unroll
        for (int j = 0; j < 8; j++) acc[j] *= sc;
    }
    f16x8 bo;
#pragma unroll
    for (int j = 0; j < 8; j++) bo[j] = (_Float16)(0.1f * (float)h[j] + acc[j]);
    *(f16x8*)&base[idx] = bo;
    *(f16x8*)&z0[idx] = h;
}

__device__ __forceinline__ void gathp(const int* __restrict__ off, const int2* __restrict__ pk,
                                      int node, int sub, const _Float16* __restrict__ zin,
                                      float (&A0)[8], float (&A1)[8])
{
    int s = off[node], e = off[node + 1];
    int i = s;
    for (; i + 4 <= e; i += 4) {
        int2 p0 = pk[i], p1 = pk[i + 1], p2 = pk[i + 2], p3 = pk[i + 3];
        f16x8 x0 = *(const f16x8*)&zin[(size_t)p0.x * HID + sub * 8];
        f16x8 x1 = *(const f16x8*)&zin[(size_t)p1.x * HID + sub * 8];
        f16x8 x2 = *(const f16x8*)&zin[(size_t)p2.x * HID + sub * 8];
        f16x8 x3 = *(const f16x8*)&zin[(size_t)p3.x * HID + sub * 8];
        float w0 = __int_as_float(p0.y), w1 = __int_as_float(p1.y);
        float w2 = __int_as_float(p2.y), w3 = __int_as_float(p3.y);
#pragma unroll
        for (int j = 0; j < 8; j++) {
            A0[j] += (float)x0[j] * w0 + (float)x1[j] * w1;
            A1[j] += (float)x2[j] * w2 + (float)x3[j] * w3;
        }
    }
    for (; i < e; i++) {
        int2 p = pk[i];
        float w = __int_as_float(p.y);
        f16x8 x = *(const f16x8*)&zin[(size_t)p.x * HID + sub * 8];
#pragma unroll
        for (int j = 0; j < 8; j++) A0[j] += (float)x[j] * w;
    }
}

// columns [0, 70000); vaccine columns are fixpoints handled in base_kernel
template<typename OT>
__launch_bounds__(256)
__global__ void appnp_kernel(const _Float16* __restrict__ zin, OT* __restrict__ zout,
                             const _Float16* __restrict__ base,
                             CsrP c1, CsrP c2, CsrP c3, const float* __restrict__ dinv)
{
    int t = threadIdx.x;
    int c = blockIdx.x * 16 + (t >> 4);
    int sub = t & 15;
    float A0[8] = {}, A1[8] = {};
    if (c < OP) {
        gathp(c2.off, c2.pk, c, sub, zin, A0, A1);
        gathp(c3.off, c3.pk, c, sub, zin, A0, A1);
    } else {
        gathp(c1.off, c1.pk, c - OP, sub, zin, A0, A1);
    }
    float dc = dinv[c];
    float d2 = dc * dc;
    size_t idx = (size_t)c * HID + sub * 8;
    f16x8 zi = *(const f16x8*)&zin[idx];
    f16x8 bs = *(const f16x8*)&base[idx];
    float res[8];
#pragma unroll
    for (int j = 0; j < 8; j++)
        res[j] = 0.9f * (dc * (A0[j] + A1[j]) + d2 * (float)zi[j]) + (float)bs[j];
    if constexpr (sizeof(OT) == 2) {
        f16x8 o;
#pragma unroll
        for (int j = 0; j < 8; j++) o[j] = (_Float16)res[j];
        *(f16x8*)&zout[idx] = o;
    } else {
        f32x4 o0, o1;
#pragma unroll
        for (int j = 0; j < 4; j++) { o0[j] = res[j]; o1[j] = res[j + 4]; }
        *(f32x4*)&zout[idx] = o0;
        *(f32x4*)&zout[idx + 4] = o1;
    }
}

// ---------------- weight prep (fp16 shadows) ----------------

__global__ void prep_all_kernel(const float* __restrict__ wg, const float* __restrict__ wp,
                                const float* __restrict__ wv,
                                _Float16* __restrict__ obg, _Float16* __restrict__ obp, _Float16* __restrict__ obv,
                                const float* __restrict__ wsl, const float* __restrict__ bsl,
                                const float* __restrict__ wsr,
                                _Float16* __restrict__ Wg0, _Float16* __restrict__ Wg1,
                                _Float16* __restrict__ Wp0, _Float16* __restrict__ Wp1,
                                float* __restrict__ bg0, float* __restrict__ bg1,
                                float* __restrict__ bp0, float* __restrict__ bp1)
{
    int y = blockIdx.y;
    int i = blockIdx.x * 256 + threadIdx.x;
    if (y == 0) {
        if (i < 32768) obg[i] = (_Float16)wg[i];
        if (i < 16384) obp[i] = (_Float16)wp[i];
        if (i < 8192)  obv[i] = (_Float16)wv[i];
        return;
    }
    int layer = y - 1;
    const float* WL = wsl + (size_t)layer * 4 * HID * HID;
    const float* WR = wsr + (size_t)layer * 4 * HID * HID;
    _Float16* Wg = layer ? Wg1 : Wg0;
    _Float16* Wp = layer ? Wp1 : Wp0;
    float* bg = layer ? bg1 : bg0;
    float* bp = layer ? bp1 : bp0;
    if (i < 128 * 512) {
        int nr = i >> 9, k = i & 511;
        float v;
        if (k < 128)      v = WL[0 * 16384 + nr * 128 + k];
        else if (k < 256) v = WL[2 * 16384 + nr * 128 + (k - 128)];
        else if (k < 384) v = WL[3 * 16384 + nr * 128 + (k - 256)];
        else {
            int kk = k - 384;
            v = WR[0 * 16384 + nr * 128 + kk] + WR[2 * 16384 + nr * 128 + kk] + WR[3 * 16384 + nr * 128 + kk];
        }
        Wg[i] = (_Float16)v;
    }
    if (i < 128 * 256) {
        int nr = i >> 8, k = i & 255;
        float v = (k < 128) ? WL[1 * 16384 + nr * 128 + k] : WR[1 * 16384 + nr * 128 + (k - 128)];
        Wp[i] = (_Float16)v;
    }
    if (i < 128) {
        const float* BL = bsl + (size_t)layer * 4 * HID;
        bg[i] = BL[0 * 128 + i] + BL[2 * 128 + i] + BL[3 * 128 + i];
        bp[i] = BL[1 * 128 + i];
    }
}

// ---------------- tiled MFMA GEMM, fp16, compile-time K (static unroll) ----------------
// block = 128 rows (4 waves x 32 rows); W chunk (128x32 f16 = 8 KB) in LDS, row stride 40 f16 (80 B, 16B-aligned).
// layouts (verified r2-r7, dtype-independent): A[m=lane&15][k=quad*8+j]; B: n=lane&15 same k slice;
// C/D: col=lane&15, row=quad*4+reg. Epilogue in-place on Hh (each wave touches only its own rows).

template<int KT, int K1, bool A_F32, bool SAGE>
__launch_bounds__(256)
__global__ void tgemm_kernel(const void* __restrict__ A1_, const _Float16* __restrict__ A2,
                             const _Float16* __restrict__ W, const float* __restrict__ bias,
                             float scale, _Float16* __restrict__ Hh, int M)
{
    __shared__ _Float16 lds[128 * 40];
    int t = threadIdx.x;
    int wave = t >> 6, lane = t & 63;
    int r = lane & 15, quad = lane >> 4;
    int mbase = blockIdx.x * 128 + wave * 32;
    int mm0 = min(mbase + r, M - 1);
    int mm1 = min(mbase + 16 + r, M - 1);
    const float* Af = (const float*)A1_;
    const _Float16* Ab = (const _Float16*)A1_;

    f32x4 acc[2][8];
#pragma unroll
    for (int s = 0; s < 2; s++)
#pragma unroll
        for (int n = 0; n < 8; n++) acc[s][n] = (f32x4){0.f, 0.f, 0.f, 0.f};

    int srow = t >> 1;
    int selt = (t & 1) * 16;

#pragma unroll
    for (int k0 = 0; k0 < KT; k0 += 32) {
        __syncthreads();
        {
            const _Float16* wsrc = W + (size_t)srow * KT + k0 + selt;
            f16x8 w0 = *(const f16x8*)wsrc;
            f16x8 w1 = *(const f16x8*)(wsrc + 8);
            *(f16x8*)&lds[srow * 40 + selt] = w0;
            *(f16x8*)&lds[srow * 40 + selt + 8] = w1;
        }
        f16x8 a0, a1;
        if constexpr (A_F32) {
            const float* p0 = Af + (size_t)mm0 * KT + k0 + quad * 8;
            const float* p1 = Af + (size_t)mm1 * KT + k0 + quad * 8;
            f32x4 x0 = *(const f32x4*)p0, x1 = *(const f32x4*)(p0 + 4);
            f32x4 y0 = *(const f32x4*)p1, y1 = *(const f32x4*)(p1 + 4);
#pragma unroll
            for (int j = 0; j < 4; j++) { a0[j] = (_Float16)x0[j]; a0[j + 4] = (_Float16)x1[j]; }
#pragma unroll
            for (int j = 0; j < 4; j++) { a1[j] = (_Float16)y0[j]; a1[j + 4] = (_Float16)y1[j]; }
        } else if (k0 < K1) {
            a0 = *(const f16x8*)(Ab + (size_t)mm0 * K1 + k0 + quad * 8);
            a1 = *(const f16x8*)(Ab + (size_t)mm1 * K1 + k0 + quad * 8);
        } else {
            a0 = *(const f16x8*)(A2 + (size_t)mm0 * 128 + (k0 - K1) + quad * 8);
            a1 = *(const f16x8*)(A2 + (size_t)mm1 * 128 + (k0 - K1) + quad * 8);
        }
        __syncthreads();
#pragma unroll
        for (int nt = 0; nt < 8; nt++) {
            f16x8 b = *(const f16x8*)&lds[(nt * 16 + r) * 40 + quad * 8];
            acc[0][nt] = __builtin_amdgcn_mfma_f32_16x16x32_f16(a0, b, acc[0][nt], 0, 0, 0);
            acc[1][nt] = __builtin_amdgcn_mfma_f32_16x16x32_f16(a1, b, acc[1][nt], 0, 0, 0);
        }
    }

#pragma unroll
    for (int sub = 0; sub < 2; sub++) {
#pragma unroll
        for (int nt = 0; nt < 8; nt++) {
            int n = nt * 16 + r;
            float bv = bias[n];
#pragma unroll
            for (int i = 0; i < 4; i++) {
                int row = mbase + sub * 16 + quad * 4 + i;
                if (row >= M) continue;
                size_t idx = (size_t)row * HID + n;
                float v;
                if constexpr (SAGE) v = fmaxf((float)Hh[idx] + (acc[sub][nt][i] + bv) * scale, 0.f);
                else                v = fmaxf(acc[sub][nt][i] + bv, 0.f);
                Hh[idx] = (_Float16)v;
            }
        }
    }
}

// ---------------- driver ----------------

extern "C" void kernel_launch(void* const* d_in, const int* in_sizes, int n_in,
                              void* d_out, int out_size, void* d_ws, size_t ws_size,
                              hipStream_t stream)
{
    (void)in_sizes; (void)n_in; (void)out_size; (void)ws_size;

    const float* x_gene = (const float*)d_in[0];
    const float* x_path = (const float*)d_in[1];
    const float* x_vacc = (const float*)d_in[2];
    const float* win_g  = (const float*)d_in[3];
    const float* bin_g  = (const float*)d_in[4];
    const float* win_p  = (const float*)d_in[5];
    const float* bin_p  = (const float*)d_in[6];
    const float* win_v  = (const float*)d_in[7];
    const float* bin_v  = (const float*)d_in[8];
    const float* wsl    = (const float*)d_in[9];
    const float* bsl    = (const float*)d_in[10];
    const float* wsr    = (const float*)d_in[11];
    const int* ei_tg  = (const int*)d_in[12];
    const int* ei_ing = (const int*)d_in[13];
    const int* ei_ct  = (const int*)d_in[14];
    const int* ei_ii  = (const int*)d_in[15];

    char* p = (char*)d_ws;
    auto alloc = [&](size_t b) { char* r = p; p += (b + 255) & ~((size_t)255); return r; };

    _Float16* Hh   = (_Float16*)alloc((size_t)N_TOT * HID * 2);
    _Float16* BASE = (_Float16*)alloc((size_t)OV * HID * 2);
    _Float16* Z1   = (_Float16*)alloc((size_t)OV * HID * 2);
    _Float16* Z2   = (_Float16*)alloc((size_t)OV * HID * 2);
    _Float16* AGG_G = (_Float16*)alloc((size_t)N_GENE * 384 * 2);
    _Float16* AGG_P = (_Float16*)alloc((size_t)N_PATH * 128 * 2);
    float* dinv   = (float*)alloc((size_t)N_TOT * 4);
    int* r_rows[4], *r_off[4];
    for (int r = 0; r < 4; r++) r_rows[r] = (int*)alloc((size_t)E_PER * 4);
    r_off[0] = (int*)alloc((size_t)(N_GENE + 1) * 4);
    r_off[1] = (int*)alloc((size_t)(N_PATH + 1) * 4);
    r_off[2] = (int*)alloc((size_t)(N_GENE + 1) * 4);
    r_off[3] = (int*)alloc((size_t)(N_GENE + 1) * 4);
    int2* pk1 = (int2*)alloc((size_t)E_PER * 8);
    int2* pk2 = (int2*)alloc((size_t)E_PER * 8);
    int2* pk3 = (int2*)alloc((size_t)E_PER * 8);
    int* rank = (int*)alloc((size_t)4 * E_PER * 4);
    int* partials = (int*)alloc((size_t)4 * 32 * 4);
    _Float16* wh_g = (_Float16*)alloc((size_t)HID * 256 * 2);
    _Float16* wh_p = (_Float16*)alloc((size_t)HID * 128 * 2);
    _Float16* wh_v = (_Float16*)alloc((size_t)HID * 64 * 2);
    _Float16* Wg[2]; _Float16* Wp[2]; float* bg[2]; float* bp[2];
    for (int l = 0; l < 2; l++) {
        Wg[l] = (_Float16*)alloc((size_t)128 * 512 * 2);
        Wp[l] = (_Float16*)alloc((size_t)128 * 256 * 2);
        bg[l] = (float*)alloc(128 * 4);
        bp[l] = (float*)alloc(128 * 4);
    }
    char* zb = p;
    int* cnt = (int*)alloc((size_t)CNT_TOTAL * 4);
    hipMemsetAsync(zb, 0, (size_t)(p - zb), stream);

    Off4 offs;
    offs.p[0] = r_off[0]; offs.p[1] = r_off[1]; offs.p[2] = r_off[2]; offs.p[3] = r_off[3];

    const int GE = (E_PER + 255) / 256;
    const int TB_G = (N_GENE + 127) / 128;   // 391
    const int TB_P = (N_PATH + 127) / 128;   // 157
    const int TB_V = (N_VACC + 127) / 128;   // 79

    prep_all_kernel<<<dim3(256, 3), 256, 0, stream>>>(win_g, win_p, win_v, wh_g, wh_p, wh_v,
                                                      wsl, bsl, wsr, Wg[0], Wg[1], Wp[0], Wp[1],
                                                      bg[0], bg[1], bp[0], bp[1]);

    Cnt4 c4;
    c4.s[0] = {ei_tg + E_PER,  cnt + 0};
    c4.s[1] = {ei_ing + E_PER, cnt + 50000};
    c4.s[2] = {ei_ct + E_PER,  cnt + 70000};
    c4.s[3] = {ei_ii + E_PER,  cnt + 120000};
    count4_kernel<<<dim3(GE, 4), 256, 0, stream>>>(c4, rank);

    dim3 sg((N_GENE + 4095) / 4096, 4);
    scan1_kernel<<<sg, 256, 0, stream>>>(cnt, partials);
    scan2_kernel<<<1, 64, 0, stream>>>(partials, offs);
    scan3_kernel<<<sg, 256, 0, stream>>>(cnt, partials, offs);

    dinv_kernel<<<(N_TOT + 255) / 256, 256, 0, stream>>>(r_off[0], r_off[1], r_off[2], r_off[3], dinv);

    F4 f4;
    f4.s[0] = {ei_tg,  r_off[0], r_rows[0], nullptr, OV};
    f4.s[1] = {ei_ing, r_off[1], r_rows[1], pk1,     OG};
    f4.s[2] = {ei_ct,  r_off[2], r_rows[2], pk2,     OP};
    f4.s[3] = {ei_ii,  r_off[3], r_rows[3], pk3,     OG};
    fill4_kernel<<<dim3(GE, 4), 256, 0, stream>>>(f4, rank, dinv);

    // --- input projections (templated, static K) ---
    tgemm_kernel<256, 256, true, false><<<TB_G, 256, 0, stream>>>(x_gene, nullptr, wh_g, bin_g, 1.f, Hh, N_GENE);
    tgemm_kernel<128, 128, true, false><<<TB_P, 256, 0, stream>>>(x_path, nullptr, wh_p, bin_p, 1.f,
                                                                  Hh + (size_t)OP * HID, N_PATH);
    tgemm_kernel< 64,  64, true, false><<<TB_V, 256, 0, stream>>>(x_vacc, nullptr, wh_v, bin_v, 1.f,
                                                                  Hh + (size_t)OV * HID, N_VACC);

    // --- 2 hetero-SAGE layers ---
    for (int l = 0; l < 2; l++) {
        Agg4 ag;
        ag.s[0] = {r_rows[0], r_off[0], AGG_G + 0,   384, N_GENE};
        ag.s[1] = {r_rows[2], r_off[2], AGG_G + 128, 384, N_GENE};
        ag.s[2] = {r_rows[3], r_off[3], AGG_G + 256, 384, N_GENE};
        ag.s[3] = {r_rows[1], r_off[1], AGG_P,       128, N_PATH};
        agg_all_kernel<<<dim3((N_GENE + 15) / 16, 4), 256, 0, stream>>>(ag, Hh);

        tgemm_kernel<512, 384, false, true><<<TB_G, 256, 0, stream>>>(AGG_G, Hh, Wg[l], bg[l],
                                                                      1.0f / 3.0f, Hh, N_GENE);
        tgemm_kernel<256, 128, false, true><<<TB_P, 256, 0, stream>>>(AGG_P, Hh + (size_t)OP * HID, Wp[l], bp[l],
                                                                      1.0f, Hh + (size_t)OP * HID, N_PATH);
    }

    // --- APPNP over genes+pathways (vaccine rows fixpoint, written by base) ---
    float* dout = (float*)d_out;
    base_kernel<<<N_TOT / 16, 256, 0, stream>>>(Hh, r_rows[0], r_off[0], dinv, BASE, Z1, dout);

    CsrP c1 = {r_off[1], pk1};
    CsrP c2 = {r_off[2], pk2};
    CsrP c3 = {r_off[3], pk3};
    const int GA = OV / 16;
    appnp_kernel<<<GA, 256, 0, stream>>>(Z1, Z2, BASE, c1, c2, c3, dinv);
    appnp_kernel<<<GA, 256, 0, stream>>>(Z2, Z1, BASE, c1, c2, c3, dinv);
    appnp_kernel<<<GA, 256, 0, stream>>>(Z1, Z2, BASE, c1, c2, c3, dinv);
    appnp_kernel<<<GA, 256, 0, stream>>>(Z2, Z1, BASE, c1, c2, c3, dinv);
    appnp_kernel<<<GA, 256, 0, stream>>>(Z1, Z2, BASE, c1, c2, c3, dinv);
    appnp_kernel<<<GA, 256, 0, stream>>>(Z2, Z1, BASE, c1, c2, c3, dinv);
    appnp_kernel<<<GA, 256, 0, stream>>>(Z1, Z2, BASE, c1, c2, c3, dinv);
    appnp_kernel<<<GA, 256, 0, stream>>>(Z2, dout, BASE, c1, c2, c3, dinv);
}